// Round 7
// baseline (790.678 us; speedup 1.0000x reference)
//
#include <hip/hip_runtime.h>
#include <stdint.h>

typedef _Float16 f16;
typedef _Float16 f16x8 __attribute__((ext_vector_type(8)));
typedef _Float16 f16x4 __attribute__((ext_vector_type(4)));
typedef float f32x4 __attribute__((ext_vector_type(4)));

#define S_TOK 8192
#define DDIM  512
#define L2E   1.44269504088896340736f
#define QSCALE 0.04419417382415922f   // 1/sqrt(512)
#define NSLOT 320
#define GTOT  8320                    // total KVB=32 iterations over all 64 tiles

__device__ __forceinline__ void gload_lds16(const void* g, void* l) {
  __builtin_amdgcn_global_load_lds((const __attribute__((address_space(1))) void*)g,
                                   (__attribute__((address_space(3))) void*)l, 16, 0, 0);
}

// DPP 16-lane (row) reductions — pure VALU, no LDS pipe.
template <int C>
__device__ __forceinline__ float fdpp(float x) {
  return __builtin_bit_cast(float,
      __builtin_amdgcn_update_dpp(0, __builtin_bit_cast(int, x), C, 0xF, 0xF, true));
}
__device__ __forceinline__ float rowmax16(float x) {
  x = fmaxf(x, fdpp<0xB1>(x));    // quad_perm [1,0,3,2]  (xor1)
  x = fmaxf(x, fdpp<0x4E>(x));    // quad_perm [2,3,0,1]  (xor2)
  x = fmaxf(x, fdpp<0x141>(x));   // row_half_mirror      (xor7)
  x = fmaxf(x, fdpp<0x140>(x));   // row_mirror           (xor15)
  return x;
}
__device__ __forceinline__ float rowsum16(float x) {
  x += fdpp<0xB1>(x);
  x += fdpp<0x4E>(x);
  x += fdpp<0x141>(x);
  x += fdpp<0x140>(x);
  return x;
}

// ---------------- convert f32 -> f16 (+ slot-table init) ------------------
__global__ __launch_bounds__(256) void k_convert(
    const float* __restrict__ X, const float* __restrict__ Wq,
    const float* __restrict__ Wk, const float* __restrict__ Wv,
    f16* __restrict__ Xh, f16* __restrict__ Wh, int* __restrict__ tp) {
  const int SD = S_TOK * DDIM;
  const int DD = DDIM * DDIM;
  int gi = blockIdx.x * 256 + threadIdx.x;
  if (gi < NSLOT) tp[gi] = -1;
  int i4 = gi * 4;
  if (i4 < SD) {
    f32x4 v = *(const f32x4*)(X + i4);
    f16x4 h = {(f16)v[0], (f16)v[1], (f16)v[2], (f16)v[3]};
    *(f16x4*)(Xh + i4) = h;
  } else {
    int j = i4 - SD;
    int mat = j >> 18;
    const float* src = (mat == 0) ? Wq : (mat == 1 ? Wk : Wv);
    f32x4 v = *(const f32x4*)(src + (j & (DD - 1)));
    f16x4 h = {(f16)v[0], (f16)v[1], (f16)v[2], (f16)v[3]};
    *(f16x4*)(Wh + j) = h;
  }
}

// ---------------- QKV projection ------------------------------------------
// Q,K row-major (Q pre-scaled). V in packed MFMA-B-frag order (K=32 blocks):
// frag(K=s/32, f=d/16) at byte (K*32+f)*1024 + lane*16 + j*2, holding
// V[K*32 + (lane>>4)*8 + j][f*16 + (lane&15)]
__global__ __launch_bounds__(256) void k_proj(
    const f16* __restrict__ Xh, const f16* __restrict__ Wh,
    f16* __restrict__ Qh, f16* __restrict__ Kh, f16* __restrict__ VB) {
  __shared__ __align__(16) char Al[128 * 128];
  __shared__ __align__(16) char Bl[128 * 128];
  const int tid = threadIdx.x;
  const int w = tid >> 6, lane = tid & 63;
  const int m0 = blockIdx.x * 128;
  const int n0 = blockIdx.y * 128;
  const int wr = (w >> 1) * 64;
  const int wc = (w & 1) * 64;

  f32x4 acc[4][4];
#pragma unroll
  for (int i = 0; i < 4; ++i)
#pragma unroll
    for (int j = 0; j < 4; ++j) acc[i][j] = (f32x4){0.f, 0.f, 0.f, 0.f};

  const char* Xb = (const char*)Xh;
  const char* Wb = (const char*)Wh;

  for (int kb = 0; kb < DDIM; kb += 64) {
    __syncthreads();
#pragma unroll
    for (int i = 0; i < 4; ++i) {
      int ch = w * 4 + i;
      int srow = lane >> 3;
      int scol = ((lane & 7) * 16) ^ (srow << 4);
      gload_lds16(Xb + (size_t)(m0 + ch * 8 + srow) * 1024 + kb * 2 + scol, Al + ch * 1024);
      gload_lds16(Wb + (size_t)(n0 + ch * 8 + srow) * 1024 + kb * 2 + scol, Bl + ch * 1024);
    }
    __syncthreads();
#pragma unroll
    for (int ks = 0; ks < 2; ++ks) {
      f16x8 a[4], b[4];
#pragma unroll
      for (int mf = 0; mf < 4; ++mf) {
        int row = wr + mf * 16 + (lane & 15);
        int col = (ks * 64 + ((lane >> 4) * 16)) ^ ((row & 7) << 4);
        a[mf] = *(const f16x8*)(Al + row * 128 + col);
      }
#pragma unroll
      for (int nf = 0; nf < 4; ++nf) {
        int row = wc + nf * 16 + (lane & 15);
        int col = (ks * 64 + ((lane >> 4) * 16)) ^ ((row & 7) << 4);
        b[nf] = *(const f16x8*)(Bl + row * 128 + col);
      }
#pragma unroll
      for (int mf = 0; mf < 4; ++mf)
#pragma unroll
        for (int nf = 0; nf < 4; ++nf)
          acc[mf][nf] = __builtin_amdgcn_mfma_f32_16x16x32_f16(a[mf], b[nf], acc[mf][nf], 0, 0, 0);
    }
  }
  int mat = n0 >> 9;
  int nbase = n0 & 511;
  if (mat == 2) {
#pragma unroll
    for (int mf = 0; mf < 4; ++mf) {
      int R0 = m0 + wr + mf * 16 + (lane >> 4) * 4;   // 4-aligned token row
      int K = R0 >> 5;
      int lhi = ((R0 >> 3) & 3) * 16;
      int j0 = R0 & 7;                                // 0 or 4
#pragma unroll
      for (int nf = 0; nf < 4; ++nf) {
        int col = nbase + wc + nf * 16 + (lane & 15);
        f16x4 h = {(f16)acc[mf][nf][0], (f16)acc[mf][nf][1],
                   (f16)acc[mf][nf][2], (f16)acc[mf][nf][3]};
        *(f16x4*)((char*)VB + (size_t)(K * 32 + (col >> 4)) * 1024 +
                  (lhi + (col & 15)) * 16 + j0 * 2) = h;
      }
    }
  } else {
    f16* dst = (mat == 0) ? Qh : Kh;
    float scale = (mat == 0) ? QSCALE : 1.0f;
#pragma unroll
    for (int mf = 0; mf < 4; ++mf)
#pragma unroll
      for (int nf = 0; nf < 4; ++nf)
#pragma unroll
        for (int r = 0; r < 4; ++r) {
          int row = m0 + wr + mf * 16 + (lane >> 4) * 4 + r;
          int col = nbase + wc + nf * 16 + (lane & 15);
          dst[(size_t)row * DDIM + col] = (f16)(acc[mf][nf][r] * scale);
        }
  }
}

// ---------------- causal flash attention, v7 -------------------------------
// v5 skeleton (BM=128, KVB=32, 8 waves, 1 barrier/iter, split-KV, dbuf K,
// in-reg DPP softmax, wave-private P bounce) with V read DIRECTLY from
// global (L2/LLC) in packed B-frag order via an 8-deep static prefetch
// ring — deletes all V LDS staging + reads (the LDS pipe was the
// bottleneck resource).
__global__ __launch_bounds__(512, 2) void k_flash(
    const f16* __restrict__ Qh, const f16* __restrict__ Kh,
    const f16* __restrict__ VBg, f16* __restrict__ Opart,
    float* __restrict__ Mpart, float* __restrict__ Lpart,
    int* __restrict__ TilePart) {
  __shared__ __align__(16) char Kl[2][32768];   // K tile [32][512 f16] swizzled
  __shared__ __align__(16) char Pl[8][1024];    // per-wave P [16][32] f16 swz

  const int tid = threadIdx.x;
  const int w = tid >> 6, lane = tid & 63;
  const int l15 = lane & 15, l4 = lane >> 4;

  int bid = blockIdx.x;
  int b = (bid & 7) * 32 + (bid >> 3);          // XCD-contiguous logical id
  int g  = (GTOT * b) >> 8;
  int g1 = (GTOT * (b + 1)) >> 8;
  int t = 0;
  while (2 * (t + 1) * (t + 2) <= g) ++t;

  const char* Kb = (const char*)Kh;
  const char* Vb = (const char*)VBg;

#define STAGEK(KB, BI) do {                                                    \
    _Pragma("unroll")                                                          \
    for (int i_ = 0; i_ < 4; ++i_) {                                           \
      int row_ = w * 4 + i_;                                                   \
      int scol_ = (lane * 16) ^ ((row_ & 7) << 4);                             \
      gload_lds16(Kb + (size_t)((KB) + row_) * 1024 + scol_, Kl[BI] + row_ * 1024); \
    } } while (0)

  while (g < g1) {
    int Ct  = 2 * t * (t + 1);
    int Ct1 = 2 * (t + 1) * (t + 2);
    int gend = min(g1, Ct1);
    int n = gend - g;
    int kb0 = (g - Ct) * 32;
    int q0 = t * 128;
    int slot = b + t;

    // Q fragments: rows q0 + w*16 + l15, full D
    f16x8 qf[16];
    {
      const f16* qp = Qh + (size_t)(q0 + w * 16 + l15) * DDIM + l4 * 8;
#pragma unroll
      for (int ks = 0; ks < 16; ++ks) qf[ks] = *(const f16x8*)(qp + ks * 32);
    }
    f32x4 acc[32];
#pragma unroll
    for (int i = 0; i < 32; ++i) acc[i] = (f32x4){0.f, 0.f, 0.f, 0.f};
    float mreg[4], lreg[4];
#pragma unroll
    for (int r = 0; r < 4; ++r) { mreg[r] = -3.0e38f; lreg[r] = 0.f; }

    // prologue: stage K tile 0, wait, open steady state
    STAGEK(kb0, 0);
    asm volatile("s_waitcnt vmcnt(0)" ::: "memory");
    __builtin_amdgcn_s_barrier();

    for (int it = 0; it < n; ++it) {
      int cur = it & 1;
      int kb = kb0 + it * 32;
      if (it + 1 < n) STAGEK(kb + 32, cur ^ 1);

      // ---- QK^T(it): S[16 x 32] per wave over d=512
      const char* KlB = Kl[cur];
      f32x4 s0 = (f32x4){0.f, 0.f, 0.f, 0.f};
      f32x4 s1 = (f32x4){0.f, 0.f, 0.f, 0.f};
      __builtin_amdgcn_s_setprio(1);
#pragma unroll
      for (int ks = 0; ks < 16; ++ks) {
        int off = ks * 64 + l4 * 16;
        f16x8 kf0 = *(const f16x8*)(KlB + l15 * 1024 + (off ^ ((l15 & 7) << 4)));
        s0 = __builtin_amdgcn_mfma_f32_16x16x32_f16(qf[ks], kf0, s0, 0, 0, 0);
        f16x8 kf1 = *(const f16x8*)(KlB + (16 + l15) * 1024 + (off ^ ((l15 & 7) << 4)));
        s1 = __builtin_amdgcn_mfma_f32_16x16x32_f16(qf[ks], kf1, s1, 0, 0, 0);
      }
      __builtin_amdgcn_s_setprio(0);

      // ---- V prefetch ring: first 8 fragments issued under softmax
      const char* vsb = Vb + (size_t)kb * 1024 + lane * 16;
      f16x8 vbuf[8];
#pragma unroll
      for (int i = 0; i < 8; ++i) vbuf[i] = *(const f16x8*)(vsb + i * 1024);

      // ---- softmax (in-reg, DPP row reductions; wave-private stats)
      {
        float p0[4], p1[4], mx[4];
        int qrb = q0 + w * 16 + l4 * 4;
        int kc = kb + l15;
#pragma unroll
        for (int r = 0; r < 4; ++r) {
          int qr = qrb + r;
          float x0 = (kc      <= qr) ? s0[r] : -3.0e38f;
          float x1 = (kc + 16 <= qr) ? s1[r] : -3.0e38f;
          p0[r] = x0; p1[r] = x1;
          mx[r] = rowmax16(fmaxf(x0, x1));
        }
        bool need = (mx[0] > mreg[0] + 8.f) || (mx[1] > mreg[1] + 8.f) ||
                    (mx[2] > mreg[2] + 8.f) || (mx[3] > mreg[3] + 8.f);
        if (__any(need)) {                       // T13 defer-rescale, THR=8
          float alpha[4];
#pragma unroll
          for (int r = 0; r < 4; ++r) {
            float mn = fmaxf(mreg[r], mx[r]);
            alpha[r] = exp2f((mreg[r] - mn) * L2E);
            lreg[r] *= alpha[r];
            mreg[r] = mn;
          }
#pragma unroll
          for (int nf = 0; nf < 32; ++nf) {
            acc[nf][0] *= alpha[0];
            acc[nf][1] *= alpha[1];
            acc[nf][2] *= alpha[2];
            acc[nf][3] *= alpha[3];
          }
        }
#pragma unroll
        for (int r = 0; r < 4; ++r) {
          int qr = qrb + r;
          float e0 = (kc      <= qr) ? exp2f((p0[r] - mreg[r]) * L2E) : 0.f;
          float e1 = (kc + 16 <= qr) ? exp2f((p1[r] - mreg[r]) * L2E) : 0.f;
          p0[r] = e0; p1[r] = e1;
          lreg[r] += rowsum16(e0 + e1);
        }
        // P write, wave-private: byte = row*64 + ((col*2) ^ sw(row))
        char* Pw = Pl[w];
#pragma unroll
        for (int r = 0; r < 4; ++r) {
          int row = l4 * 4 + r;
          int sw = (((row & 3) ^ (row >> 2)) & 3) << 4;
          *(f16*)(Pw + row * 64 + ((l15 * 2) ^ sw))        = (f16)p0[r];
          *(f16*)(Pw + row * 64 + (((16 + l15) * 2) ^ sw)) = (f16)p1[r];
        }
      }
      asm volatile("s_waitcnt lgkmcnt(0)" ::: "memory");  // P committed
      __builtin_amdgcn_sched_barrier(0);

      // ---- PV(it): O[16 x 512] += P[16 x 32] @ V[32 x 512], V from global
      {
        char* Pw = Pl[w];
        int prow = l15;
        int sw = (((prow & 3) ^ (prow >> 2)) & 3) << 4;
        f16x8 pa = *(const f16x8*)(Pw + prow * 64 + ((l4 * 16) ^ sw));
        __builtin_amdgcn_s_setprio(1);
#pragma unroll
        for (int nf = 0; nf < 32; ++nf) {
          f16x8 vv = vbuf[nf & 7];
          if (nf + 8 < 32) vbuf[nf & 7] = *(const f16x8*)(vsb + (nf + 8) * 1024);
          acc[nf] = __builtin_amdgcn_mfma_f32_16x16x32_f16(pa, vv, acc[nf], 0, 0, 0);
        }
        __builtin_amdgcn_s_setprio(0);
      }

      asm volatile("s_waitcnt vmcnt(0)" ::: "memory");  // staging issued a full phase ago
      __builtin_amdgcn_s_barrier();
    }

    // ---- epilogue: all stats in-reg (DPP-reduced => uniform per row group)
    {
      float inv[4];
#pragma unroll
      for (int r = 0; r < 4; ++r) inv[r] = (lreg[r] > 0.f) ? 1.f / lreg[r] : 0.f;
      f16* op = Opart + (size_t)slot * (128 * 512);
      int rowb = w * 16 + l4 * 4;
#pragma unroll
      for (int nf = 0; nf < 32; ++nf) {
        int col = nf * 16 + l15;
#pragma unroll
        for (int r = 0; r < 4; ++r)
          op[(size_t)(rowb + r) * 512 + col] = (f16)(acc[nf][r] * inv[r]);
      }
      if (l15 == 0) {
#pragma unroll
        for (int r = 0; r < 4; ++r) {
          Mpart[slot * 128 + rowb + r] = mreg[r];
          Lpart[slot * 128 + rowb + r] = lreg[r];
        }
      }
      if (tid == 0) TilePart[slot] = t;
    }
    g = gend;
    ++t;
  }
#undef STAGEK
}

// ---------------- combine partials -> out --------------------------------
__global__ __launch_bounds__(256) void k_reduce(
    const f16* __restrict__ Opart, const float* __restrict__ Mpart,
    const float* __restrict__ Lpart, const int* __restrict__ TilePart,
    float* __restrict__ out) {
  __shared__ int tp[NSLOT];
  __shared__ int sl[16];
  __shared__ int scnt;
  int tid = threadIdx.x;
  int t = blockIdx.x >> 2, rg = blockIdx.x & 3;
  for (int s = tid; s < NSLOT; s += 256) tp[s] = TilePart[s];
  __syncthreads();
  if (tid == 0) {
    int c = 0;
    for (int s = 0; s < NSLOT; ++s)
      if (tp[s] == t && c < 16) sl[c++] = s;
    scnt = c;
  }
  __syncthreads();
  int cnt = scnt;
  int rowIn = rg * 32 + (tid >> 3);
  int row = t * 128 + rowIn;
  int col0 = (tid & 7) * 64;

  float M = -3.0e38f;
  for (int i = 0; i < cnt; ++i) M = fmaxf(M, Mpart[sl[i] * 128 + rowIn]);
  float a[64];
#pragma unroll
  for (int j = 0; j < 64; ++j) a[j] = 0.f;
  float denom = 0.f;
  for (int i = 0; i < cnt; ++i) {
    int s = sl[i];
    float m = Mpart[s * 128 + rowIn];
    float l = Lpart[s * 128 + rowIn];
    float wgt = exp2f((m - M) * L2E) * l;
    denom += wgt;
    const f16* op = Opart + (size_t)s * 65536 + rowIn * 512 + col0;
#pragma unroll
    for (int v = 0; v < 8; ++v) {
      f16x8 x = *(const f16x8*)(op + v * 8);
#pragma unroll
      for (int j = 0; j < 8; ++j) a[v * 8 + j] += wgt * (float)x[j];
    }
  }
  float inv = (denom > 0.f) ? 1.f / denom : 0.f;
  float* o = out + (size_t)row * 512 + col0;
#pragma unroll
  for (int j = 0; j < 64; ++j) o[j] = a[j] * inv;
}

extern "C" void kernel_launch(void* const* d_in, const int* in_sizes, int n_in,
                              void* d_out, int out_size, void* d_ws, size_t ws_size,
                              hipStream_t stream) {
  const float* X  = (const float*)d_in[0];
  const float* Wq = (const float*)d_in[2];
  const float* Wk = (const float*)d_in[3];
  const float* Wv = (const float*)d_in[4];
  float* out = (float*)d_out;

  char* ws = (char*)d_ws;
  f16*   Opart = (f16*)(ws);                               // 40 MiB
  float* Mpart = (float*)(ws + (40u << 20));               // 160 KiB
  float* Lpart = (float*)(ws + (41u << 20));               // 160 KiB
  int*   TileP = (int*)(ws + (42u << 20));                 // 1.25 KiB
  f16* Qh = (f16*)(ws + (43u << 20));                      // 8 MiB (pre-scaled)
  f16* Kh = (f16*)(ws + (51u << 20));                      // 8 MiB
  f16* VB = (f16*)(ws + (59u << 20));                      // 8 MiB packed frags
  f16* Xh = (f16*)(ws + (67u << 20));                      // 8 MiB
  f16* Wh = (f16*)(ws + (75u << 20));                      // 1.5 MiB

  k_convert<<<4864, 256, 0, stream>>>(X, Wq, Wk, Wv, Xh, Wh, TileP);
  dim3 gp(64, 12);
  k_proj<<<gp, 256, 0, stream>>>(Xh, Wh, Qh, Kh, VB);
  k_flash<<<256, 512, 0, stream>>>(Qh, Kh, VB, Opart, Mpart, Lpart, TileP);
  k_reduce<<<256, 256, 0, stream>>>(Opart, Mpart, Lpart, TileP, out);
}

// Round 8
// 331.520 us; speedup vs baseline: 2.3850x; 2.3850x over previous
//
#include <hip/hip_runtime.h>
#include <stdint.h>

typedef _Float16 f16;
typedef _Float16 f16x8 __attribute__((ext_vector_type(8)));
typedef _Float16 f16x4 __attribute__((ext_vector_type(4)));
typedef float f32x4 __attribute__((ext_vector_type(4)));

#define S_TOK 8192
#define DDIM  512
#define L2E   1.44269504088896340736f
#define QSCALE 0.04419417382415922f   // 1/sqrt(512)
#define NSLOT 640
#define GTOT  16512                   // sum over 128 tiles of (2t+2) KVB=32 iters

__device__ __forceinline__ void gload_lds16(const void* g, void* l) {
  __builtin_amdgcn_global_load_lds((const __attribute__((address_space(1))) void*)g,
                                   (__attribute__((address_space(3))) void*)l, 16, 0, 0);
}

// DPP 16-lane (row) reductions — pure VALU, no LDS pipe.
template <int C>
__device__ __forceinline__ float fdpp(float x) {
  return __builtin_bit_cast(float,
      __builtin_amdgcn_update_dpp(0, __builtin_bit_cast(int, x), C, 0xF, 0xF, true));
}
__device__ __forceinline__ float rowmax16(float x) {
  x = fmaxf(x, fdpp<0xB1>(x));    // quad_perm [1,0,3,2]  (xor1)
  x = fmaxf(x, fdpp<0x4E>(x));    // quad_perm [2,3,0,1]  (xor2)
  x = fmaxf(x, fdpp<0x141>(x));   // row_half_mirror
  x = fmaxf(x, fdpp<0x140>(x));   // row_mirror
  return x;
}
__device__ __forceinline__ float rowsum16(float x) {
  x += fdpp<0xB1>(x);
  x += fdpp<0x4E>(x);
  x += fdpp<0x141>(x);
  x += fdpp<0x140>(x);
  return x;
}

// ---------------- convert f32 -> f16 (+ slot-table init) ------------------
__global__ __launch_bounds__(256) void k_convert(
    const float* __restrict__ X, const float* __restrict__ Wq,
    const float* __restrict__ Wk, const float* __restrict__ Wv,
    f16* __restrict__ Xh, f16* __restrict__ Wh, int* __restrict__ tp) {
  const int SD = S_TOK * DDIM;
  const int DD = DDIM * DDIM;
  int gi = blockIdx.x * 256 + threadIdx.x;
  if (gi < NSLOT) tp[gi] = -1;
  int i4 = gi * 4;
  if (i4 < SD) {
    f32x4 v = *(const f32x4*)(X + i4);
    f16x4 h = {(f16)v[0], (f16)v[1], (f16)v[2], (f16)v[3]};
    *(f16x4*)(Xh + i4) = h;
  } else {
    int j = i4 - SD;
    int mat = j >> 18;
    const float* src = (mat == 0) ? Wq : (mat == 1 ? Wk : Wv);
    f32x4 v = *(const f32x4*)(src + (j & (DD - 1)));
    f16x4 h = {(f16)v[0], (f16)v[1], (f16)v[2], (f16)v[3]};
    *(f16x4*)(Wh + j) = h;
  }
}

// ---------------- QKV projection ------------------------------------------
// Q,K row-major (Q pre-scaled). V in packed MFMA-B-frag order (K=32 blocks):
// frag(K=s/32, f=d/16) at byte (K*32+f)*1024 + lane*16 + j*2, holding
// V[K*32 + (lane>>4)*8 + j][f*16 + (lane&15)]
__global__ __launch_bounds__(256) void k_proj(
    const f16* __restrict__ Xh, const f16* __restrict__ Wh,
    f16* __restrict__ Qh, f16* __restrict__ Kh, f16* __restrict__ VB) {
  __shared__ __align__(16) char Al[128 * 128];
  __shared__ __align__(16) char Bl[128 * 128];
  const int tid = threadIdx.x;
  const int w = tid >> 6, lane = tid & 63;
  const int m0 = blockIdx.x * 128;
  const int n0 = blockIdx.y * 128;
  const int wr = (w >> 1) * 64;
  const int wc = (w & 1) * 64;

  f32x4 acc[4][4];
#pragma unroll
  for (int i = 0; i < 4; ++i)
#pragma unroll
    for (int j = 0; j < 4; ++j) acc[i][j] = (f32x4){0.f, 0.f, 0.f, 0.f};

  const char* Xb = (const char*)Xh;
  const char* Wb = (const char*)Wh;

  for (int kb = 0; kb < DDIM; kb += 64) {
    __syncthreads();
#pragma unroll
    for (int i = 0; i < 4; ++i) {
      int ch = w * 4 + i;
      int srow = lane >> 3;
      int scol = ((lane & 7) * 16) ^ (srow << 4);
      gload_lds16(Xb + (size_t)(m0 + ch * 8 + srow) * 1024 + kb * 2 + scol, Al + ch * 1024);
      gload_lds16(Wb + (size_t)(n0 + ch * 8 + srow) * 1024 + kb * 2 + scol, Bl + ch * 1024);
    }
    __syncthreads();
#pragma unroll
    for (int ks = 0; ks < 2; ++ks) {
      f16x8 a[4], b[4];
#pragma unroll
      for (int mf = 0; mf < 4; ++mf) {
        int row = wr + mf * 16 + (lane & 15);
        int col = (ks * 64 + ((lane >> 4) * 16)) ^ ((row & 7) << 4);
        a[mf] = *(const f16x8*)(Al + row * 128 + col);
      }
#pragma unroll
      for (int nf = 0; nf < 4; ++nf) {
        int row = wc + nf * 16 + (lane & 15);
        int col = (ks * 64 + ((lane >> 4) * 16)) ^ ((row & 7) << 4);
        b[nf] = *(const f16x8*)(Bl + row * 128 + col);
      }
#pragma unroll
      for (int mf = 0; mf < 4; ++mf)
#pragma unroll
        for (int nf = 0; nf < 4; ++nf)
          acc[mf][nf] = __builtin_amdgcn_mfma_f32_16x16x32_f16(a[mf], b[nf], acc[mf][nf], 0, 0, 0);
    }
  }
  int mat = n0 >> 9;
  int nbase = n0 & 511;
  if (mat == 2) {
#pragma unroll
    for (int mf = 0; mf < 4; ++mf) {
      int R0 = m0 + wr + mf * 16 + (lane >> 4) * 4;   // 4-aligned token row
      int K = R0 >> 5;
      int lhi = ((R0 >> 3) & 3) * 16;
      int j0 = R0 & 7;                                // 0 or 4
#pragma unroll
      for (int nf = 0; nf < 4; ++nf) {
        int col = nbase + wc + nf * 16 + (lane & 15);
        f16x4 h = {(f16)acc[mf][nf][0], (f16)acc[mf][nf][1],
                   (f16)acc[mf][nf][2], (f16)acc[mf][nf][3]};
        *(f16x4*)((char*)VB + (size_t)(K * 32 + (col >> 4)) * 1024 +
                  (lhi + (col & 15)) * 16 + j0 * 2) = h;
      }
    }
  } else {
    f16* dst = (mat == 0) ? Qh : Kh;
    float scale = (mat == 0) ? QSCALE : 1.0f;
#pragma unroll
    for (int mf = 0; mf < 4; ++mf)
#pragma unroll
      for (int nf = 0; nf < 4; ++nf)
#pragma unroll
        for (int r = 0; r < 4; ++r) {
          int row = m0 + wr + mf * 16 + (lane >> 4) * 4 + r;
          int col = nbase + wc + nf * 16 + (lane & 15);
          dst[(size_t)row * DDIM + col] = (f16)(acc[mf][nf][r] * scale);
        }
  }
}

// ---------------- causal flash attention, v8 -------------------------------
// v5 per-wave code on 256-thread blocks: 4 waves x 16 rows = 64 q-rows/block,
// KVB=32, single-buffered K+V LDS (68.5 KB) -> 2 independent blocks/CU that
// de-phase (one block's softmax overlaps the other's LDS phases). P bounce
// stride-72 rows: conflict-free stores AND b128 A-frag read. 512 blocks,
// split-KV over GTOT=16512 iters, slot = b + t (collision-free).
__global__ __launch_bounds__(256, 2) void k_flash(
    const f16* __restrict__ Qh, const f16* __restrict__ Kh,
    const f16* __restrict__ VBg, f16* __restrict__ Opart,
    float* __restrict__ Mpart, float* __restrict__ Lpart,
    int* __restrict__ TilePart) {
  __shared__ __align__(16) char Kl[32768];   // K tile [32][512 f16] swizzled
  __shared__ __align__(16) char Vl[32768];   // V frag-packed [32 frags][1KB]
  __shared__ __align__(16) char Pl[4][1152]; // per-wave P: 16 rows x 72B

  const int tid = threadIdx.x;
  const int w = tid >> 6, lane = tid & 63;   // w in 0..3
  const int l15 = lane & 15, l4 = lane >> 4;

  int bid = blockIdx.x;
  int b = (bid & 7) * 64 + (bid >> 3);       // XCD-contiguous logical id (512=8*64)
  int g  = (GTOT * b) >> 9;
  int g1 = (GTOT * (b + 1)) >> 9;
  int t = 0;
  while ((t + 1) * (t + 2) <= g) ++t;        // tile t covers [t(t+1), (t+1)(t+2))

  const char* Kb = (const char*)Kh;
  const char* Vb = (const char*)VBg;
  char* Pw = Pl[w];

#define STAGEKV(KB) do {                                                       \
    _Pragma("unroll")                                                          \
    for (int i_ = 0; i_ < 8; ++i_) {                                           \
      int row_ = w * 8 + i_;                                                   \
      int scol_ = (lane * 16) ^ ((row_ & 7) << 4);                             \
      gload_lds16(Kb + (size_t)((KB) + row_) * 1024 + scol_, Kl + row_ * 1024);\
    }                                                                          \
    const char* vs_ = Vb + (size_t)(KB) * 1024;                                \
    _Pragma("unroll")                                                          \
    for (int i_ = 0; i_ < 8; ++i_) {                                           \
      int ch_ = w * 8 + i_;                                                    \
      gload_lds16(vs_ + ch_ * 1024 + lane * 16, Vl + ch_ * 1024);              \
    } } while (0)

  while (g < g1) {
    int Ct  = t * (t + 1);
    int Ct1 = (t + 1) * (t + 2);
    int gend = min(g1, Ct1);
    int n = gend - g;
    int kb0 = (g - Ct) * 32;
    int q0 = t * 64;
    int slot = b + t;

    // Q fragments: rows q0 + w*16 + l15, full D
    f16x8 qf[16];
    {
      const f16* qp = Qh + (size_t)(q0 + w * 16 + l15) * DDIM + l4 * 8;
#pragma unroll
      for (int ks = 0; ks < 16; ++ks) qf[ks] = *(const f16x8*)(qp + ks * 32);
    }
    f32x4 acc[32];
#pragma unroll
    for (int i = 0; i < 32; ++i) acc[i] = (f32x4){0.f, 0.f, 0.f, 0.f};
    float mreg[4], lreg[4];
#pragma unroll
    for (int r = 0; r < 4; ++r) { mreg[r] = -3.0e38f; lreg[r] = 0.f; }

    for (int it = 0; it < n; ++it) {
      int kb = kb0 + it * 32;
      STAGEKV(kb);
      __syncthreads();                       // vmcnt(0)+barrier: tile visible

      // ---- QK^T(it): S[16 x 32] per wave over d=512
      f32x4 s0 = (f32x4){0.f, 0.f, 0.f, 0.f};
      f32x4 s1 = (f32x4){0.f, 0.f, 0.f, 0.f};
      __builtin_amdgcn_s_setprio(1);
#pragma unroll
      for (int ks = 0; ks < 16; ++ks) {
        int off = ks * 64 + l4 * 16;
        f16x8 kf0 = *(const f16x8*)(Kl + l15 * 1024 + (off ^ ((l15 & 7) << 4)));
        s0 = __builtin_amdgcn_mfma_f32_16x16x32_f16(qf[ks], kf0, s0, 0, 0, 0);
        f16x8 kf1 = *(const f16x8*)(Kl + (16 + l15) * 1024 + (off ^ ((l15 & 7) << 4)));
        s1 = __builtin_amdgcn_mfma_f32_16x16x32_f16(qf[ks], kf1, s1, 0, 0, 0);
      }
      __builtin_amdgcn_s_setprio(0);

      // ---- softmax (in-reg, DPP row reductions; wave-private stats)
      {
        float p0[4], p1[4], mx[4];
        int qrb = q0 + w * 16 + l4 * 4;
        int kc = kb + l15;
#pragma unroll
        for (int r = 0; r < 4; ++r) {
          int qr = qrb + r;
          float x0 = (kc      <= qr) ? s0[r] : -3.0e38f;
          float x1 = (kc + 16 <= qr) ? s1[r] : -3.0e38f;
          p0[r] = x0; p1[r] = x1;
          mx[r] = rowmax16(fmaxf(x0, x1));
        }
        bool need = (mx[0] > mreg[0] + 8.f) || (mx[1] > mreg[1] + 8.f) ||
                    (mx[2] > mreg[2] + 8.f) || (mx[3] > mreg[3] + 8.f);
        if (__any(need)) {                   // T13 defer-rescale, THR=8
          float alpha[4];
#pragma unroll
          for (int r = 0; r < 4; ++r) {
            float mn = fmaxf(mreg[r], mx[r]);
            alpha[r] = exp2f((mreg[r] - mn) * L2E);
            lreg[r] *= alpha[r];
            mreg[r] = mn;
          }
#pragma unroll
          for (int nf = 0; nf < 32; ++nf) {
            acc[nf][0] *= alpha[0];
            acc[nf][1] *= alpha[1];
            acc[nf][2] *= alpha[2];
            acc[nf][3] *= alpha[3];
          }
        }
#pragma unroll
        for (int r = 0; r < 4; ++r) {
          int qr = qrb + r;
          p0[r] = (kc      <= qr) ? exp2f((p0[r] - mreg[r]) * L2E) : 0.f;
          p1[r] = (kc + 16 <= qr) ? exp2f((p1[r] - mreg[r]) * L2E) : 0.f;
        }
        // P write FIRST (stride-72 rows: 2-way stores), rowsum in store shadow
#pragma unroll
        for (int r = 0; r < 4; ++r) {
          int row = l4 * 4 + r;
          *(f16*)(Pw + row * 72 + l15 * 2)      = (f16)p0[r];
          *(f16*)(Pw + row * 72 + 32 + l15 * 2) = (f16)p1[r];
        }
#pragma unroll
        for (int r = 0; r < 4; ++r)
          lreg[r] += rowsum16(p0[r] + p1[r]);
      }
      asm volatile("s_waitcnt lgkmcnt(0)" ::: "memory");  // P committed
      __builtin_amdgcn_sched_barrier(0);

      // ---- PV(it): O[16 x 512] += P[16 x 32] @ V[32 x 512]
      {
        // A-frag: row l15, kv = l4*8+j -> bytes kv*2 in [0,64): single b128
        f16x8 pa = *(const f16x8*)(Pw + l15 * 72 + l4 * 16);
        __builtin_amdgcn_s_setprio(1);
#pragma unroll
        for (int nf = 0; nf < 32; ++nf) {
          f16x8 vb = *(const f16x8*)(Vl + nf * 1024 + lane * 16);
          acc[nf] = __builtin_amdgcn_mfma_f32_16x16x32_f16(pa, vb, acc[nf], 0, 0, 0);
        }
        __builtin_amdgcn_s_setprio(0);
      }
      __syncthreads();                       // all reads done before next stage
    }

    // ---- epilogue: all stats in-reg (DPP-reduced => uniform per row group)
    {
      float inv[4];
#pragma unroll
      for (int r = 0; r < 4; ++r) inv[r] = (lreg[r] > 0.f) ? 1.f / lreg[r] : 0.f;
      f16* op = Opart + (size_t)slot * (64 * 512);
      int rowb = w * 16 + l4 * 4;
#pragma unroll
      for (int nf = 0; nf < 32; ++nf) {
        int col = nf * 16 + l15;
#pragma unroll
        for (int r = 0; r < 4; ++r)
          op[(size_t)(rowb + r) * 512 + col] = (f16)(acc[nf][r] * inv[r]);
      }
      if (l15 == 0) {
#pragma unroll
        for (int r = 0; r < 4; ++r) {
          Mpart[slot * 64 + rowb + r] = mreg[r];
          Lpart[slot * 64 + rowb + r] = lreg[r];
        }
      }
      if (tid == 0) TilePart[slot] = t;
    }
    g = gend;
    ++t;
  }
#undef STAGEKV
}

// ---------------- combine partials -> out --------------------------------
__global__ __launch_bounds__(256) void k_reduce(
    const f16* __restrict__ Opart, const float* __restrict__ Mpart,
    const float* __restrict__ Lpart, const int* __restrict__ TilePart,
    float* __restrict__ out) {
  __shared__ int tp[NSLOT];
  __shared__ int sl[16];
  __shared__ int scnt;
  int tid = threadIdx.x;
  int t = blockIdx.x >> 1, rg = blockIdx.x & 1;   // 128 tiles x 2 row-groups
  for (int s = tid; s < NSLOT; s += 256) tp[s] = TilePart[s];
  __syncthreads();
  if (tid == 0) {
    int c = 0;
    for (int s = 0; s < NSLOT; ++s)
      if (tp[s] == t && c < 16) sl[c++] = s;
    scnt = c;
  }
  __syncthreads();
  int cnt = scnt;
  int rowIn = rg * 32 + (tid >> 3);               // 0..63
  int row = t * 64 + rowIn;
  int col0 = (tid & 7) * 64;

  float M = -3.0e38f;
  for (int i = 0; i < cnt; ++i) M = fmaxf(M, Mpart[sl[i] * 64 + rowIn]);
  float a[64];
#pragma unroll
  for (int j = 0; j < 64; ++j) a[j] = 0.f;
  float denom = 0.f;
  for (int i = 0; i < cnt; ++i) {
    int s = sl[i];
    float m = Mpart[s * 64 + rowIn];
    float l = Lpart[s * 64 + rowIn];
    float wgt = exp2f((m - M) * L2E) * l;
    denom += wgt;
    const f16* op = Opart + (size_t)s * 32768 + rowIn * 512 + col0;
#pragma unroll
    for (int v = 0; v < 8; ++v) {
      f16x8 x = *(const f16x8*)(op + v * 8);
#pragma unroll
      for (int j = 0; j < 8; ++j) a[v * 8 + j] += wgt * (float)x[j];
    }
  }
  float inv = (denom > 0.f) ? 1.f / denom : 0.f;
  float* o = out + (size_t)row * 512 + col0;
#pragma unroll
  for (int j = 0; j < 64; ++j) o[j] = a[j] * inv;
}

extern "C" void kernel_launch(void* const* d_in, const int* in_sizes, int n_in,
                              void* d_out, int out_size, void* d_ws, size_t ws_size,
                              hipStream_t stream) {
  const float* X  = (const float*)d_in[0];
  const float* Wq = (const float*)d_in[2];
  const float* Wk = (const float*)d_in[3];
  const float* Wv = (const float*)d_in[4];
  float* out = (float*)d_out;

  char* ws = (char*)d_ws;
  f16*   Opart = (f16*)(ws);                               // 40 MiB (640 x 64KB)
  float* Mpart = (float*)(ws + (40u << 20));               // 160 KiB
  float* Lpart = (float*)(ws + (41u << 20));               // 160 KiB
  int*   TileP = (int*)(ws + (42u << 20));                 // 2.5 KiB
  f16* Qh = (f16*)(ws + (43u << 20));                      // 8 MiB (pre-scaled)
  f16* Kh = (f16*)(ws + (51u << 20));                      // 8 MiB
  f16* VB = (f16*)(ws + (59u << 20));                      // 8 MiB packed frags
  f16* Xh = (f16*)(ws + (67u << 20));                      // 8 MiB
  f16* Wh = (f16*)(ws + (75u << 20));                      // 1.5 MiB

  k_convert<<<4864, 256, 0, stream>>>(X, Wq, Wk, Wv, Xh, Wh, TileP);
  dim3 gp(64, 12);
  k_proj<<<gp, 256, 0, stream>>>(Xh, Wh, Qh, Kh, VB);
  k_flash<<<512, 256, 0, stream>>>(Qh, Kh, VB, Opart, Mpart, Lpart, TileP);
  k_reduce<<<256, 256, 0, stream>>>(Opart, Mpart, Lpart, TileP, out);
}

// Round 9
// 250.268 us; speedup vs baseline: 3.1593x; 1.3247x over previous
//
#include <hip/hip_runtime.h>
#include <stdint.h>

typedef _Float16 f16;
typedef _Float16 f16x8 __attribute__((ext_vector_type(8)));
typedef _Float16 f16x4 __attribute__((ext_vector_type(4)));
typedef float f32x4 __attribute__((ext_vector_type(4)));

#define S_TOK 8192
#define DDIM  512
#define L2E   1.44269504088896340736f
#define QSCALE 0.04419417382415922f   // 1/sqrt(512)
#define NSLOT 320
#define GTOT  8320                    // total KVB=32 iterations over all 64 tiles

__device__ __forceinline__ void gload_lds16(const void* g, void* l) {
  __builtin_amdgcn_global_load_lds((const __attribute__((address_space(1))) void*)g,
                                   (__attribute__((address_space(3))) void*)l, 16, 0, 0);
}

// DPP 16-lane (row) reductions — pure VALU, no LDS pipe.
template <int C>
__device__ __forceinline__ float fdpp(float x) {
  return __builtin_bit_cast(float,
      __builtin_amdgcn_update_dpp(0, __builtin_bit_cast(int, x), C, 0xF, 0xF, true));
}
__device__ __forceinline__ float rowmax16(float x) {
  x = fmaxf(x, fdpp<0xB1>(x));    // quad_perm [1,0,3,2]  (xor1)
  x = fmaxf(x, fdpp<0x4E>(x));    // quad_perm [2,3,0,1]  (xor2)
  x = fmaxf(x, fdpp<0x141>(x));   // row_half_mirror
  x = fmaxf(x, fdpp<0x140>(x));   // row_mirror
  return x;
}
__device__ __forceinline__ float rowsum16(float x) {
  x += fdpp<0xB1>(x);
  x += fdpp<0x4E>(x);
  x += fdpp<0x141>(x);
  x += fdpp<0x140>(x);
  return x;
}

// ---------------- convert f32 -> f16 (+ slot-table init) ------------------
__global__ __launch_bounds__(256) void k_convert(
    const float* __restrict__ X, const float* __restrict__ Wq,
    const float* __restrict__ Wk, const float* __restrict__ Wv,
    f16* __restrict__ Xh, f16* __restrict__ Wh, int* __restrict__ tp) {
  const int SD = S_TOK * DDIM;
  const int DD = DDIM * DDIM;
  int gi = blockIdx.x * 256 + threadIdx.x;
  if (gi < NSLOT) tp[gi] = -1;
  int i4 = gi * 4;
  if (i4 < SD) {
    f32x4 v = *(const f32x4*)(X + i4);
    f16x4 h = {(f16)v[0], (f16)v[1], (f16)v[2], (f16)v[3]};
    *(f16x4*)(Xh + i4) = h;
  } else {
    int j = i4 - SD;
    int mat = j >> 18;
    const float* src = (mat == 0) ? Wq : (mat == 1 ? Wk : Wv);
    f32x4 v = *(const f32x4*)(src + (j & (DD - 1)));
    f16x4 h = {(f16)v[0], (f16)v[1], (f16)v[2], (f16)v[3]};
    *(f16x4*)(Wh + j) = h;
  }
}

// ---------------- QKV projection ------------------------------------------
// Q,K row-major (Q pre-scaled). V in packed MFMA-B-frag order (K=32 blocks):
// frag(K=s/32, f=d/16) at byte (K*32+f)*1024 + lane*16 + j*2, holding
// V[K*32 + (lane>>4)*8 + j][f*16 + (lane&15)]
__global__ __launch_bounds__(256) void k_proj(
    const f16* __restrict__ Xh, const f16* __restrict__ Wh,
    f16* __restrict__ Qh, f16* __restrict__ Kh, f16* __restrict__ VB) {
  __shared__ __align__(16) char Al[128 * 128];
  __shared__ __align__(16) char Bl[128 * 128];
  const int tid = threadIdx.x;
  const int w = tid >> 6, lane = tid & 63;
  const int m0 = blockIdx.x * 128;
  const int n0 = blockIdx.y * 128;
  const int wr = (w >> 1) * 64;
  const int wc = (w & 1) * 64;

  f32x4 acc[4][4];
#pragma unroll
  for (int i = 0; i < 4; ++i)
#pragma unroll
    for (int j = 0; j < 4; ++j) acc[i][j] = (f32x4){0.f, 0.f, 0.f, 0.f};

  const char* Xb = (const char*)Xh;
  const char* Wb = (const char*)Wh;

  for (int kb = 0; kb < DDIM; kb += 64) {
    __syncthreads();
#pragma unroll
    for (int i = 0; i < 4; ++i) {
      int ch = w * 4 + i;
      int srow = lane >> 3;
      int scol = ((lane & 7) * 16) ^ (srow << 4);
      gload_lds16(Xb + (size_t)(m0 + ch * 8 + srow) * 1024 + kb * 2 + scol, Al + ch * 1024);
      gload_lds16(Wb + (size_t)(n0 + ch * 8 + srow) * 1024 + kb * 2 + scol, Bl + ch * 1024);
    }
    __syncthreads();
#pragma unroll
    for (int ks = 0; ks < 2; ++ks) {
      f16x8 a[4], b[4];
#pragma unroll
      for (int mf = 0; mf < 4; ++mf) {
        int row = wr + mf * 16 + (lane & 15);
        int col = (ks * 64 + ((lane >> 4) * 16)) ^ ((row & 7) << 4);
        a[mf] = *(const f16x8*)(Al + row * 128 + col);
      }
#pragma unroll
      for (int nf = 0; nf < 4; ++nf) {
        int row = wc + nf * 16 + (lane & 15);
        int col = (ks * 64 + ((lane >> 4) * 16)) ^ ((row & 7) << 4);
        b[nf] = *(const f16x8*)(Bl + row * 128 + col);
      }
#pragma unroll
      for (int mf = 0; mf < 4; ++mf)
#pragma unroll
        for (int nf = 0; nf < 4; ++nf)
          acc[mf][nf] = __builtin_amdgcn_mfma_f32_16x16x32_f16(a[mf], b[nf], acc[mf][nf], 0, 0, 0);
    }
  }
  int mat = n0 >> 9;
  int nbase = n0 & 511;
  if (mat == 2) {
#pragma unroll
    for (int mf = 0; mf < 4; ++mf) {
      int R0 = m0 + wr + mf * 16 + (lane >> 4) * 4;   // 4-aligned token row
      int K = R0 >> 5;
      int lhi = ((R0 >> 3) & 3) * 16;
      int j0 = R0 & 7;                                // 0 or 4
#pragma unroll
      for (int nf = 0; nf < 4; ++nf) {
        int col = nbase + wc + nf * 16 + (lane & 15);
        f16x4 h = {(f16)acc[mf][nf][0], (f16)acc[mf][nf][1],
                   (f16)acc[mf][nf][2], (f16)acc[mf][nf][3]};
        *(f16x4*)((char*)VB + (size_t)(K * 32 + (col >> 4)) * 1024 +
                  (lhi + (col & 15)) * 16 + j0 * 2) = h;
      }
    }
  } else {
    f16* dst = (mat == 0) ? Qh : Kh;
    float scale = (mat == 0) ? QSCALE : 1.0f;
#pragma unroll
    for (int mf = 0; mf < 4; ++mf)
#pragma unroll
      for (int nf = 0; nf < 4; ++nf)
#pragma unroll
        for (int r = 0; r < 4; ++r) {
          int row = m0 + wr + mf * 16 + (lane >> 4) * 4 + r;
          int col = nbase + wc + nf * 16 + (lane & 15);
          dst[(size_t)row * DDIM + col] = (f16)(acc[mf][nf][r] * scale);
        }
  }
}

// ---------------- causal flash attention, v9 -------------------------------
// v5 skeleton (BM=128, KVB=32, 256 blocks x 8 waves, split-KV, K/V dbuf)
// software-pipelined: per iter  fused{QK^T(it) || PV(it-1)}  -> barrier ->
// stage(it+1) -> softmax(it)->P[it&1] -> vmcnt(0) -> barrier.
// P double-buffered wave-private, stride-72 rows (2-way stores, b128 A read).
__global__ __launch_bounds__(512, 2) void k_flash(
    const f16* __restrict__ Qh, const f16* __restrict__ Kh,
    const f16* __restrict__ VBg, f16* __restrict__ Opart,
    float* __restrict__ Mpart, float* __restrict__ Lpart,
    int* __restrict__ TilePart) {
  __shared__ __align__(16) char Kl[2][32768];   // K tile [32][512 f16] swizzled
  __shared__ __align__(16) char Vl[2][32768];   // V frag-packed [32 frags][1KB]
  __shared__ __align__(16) char Pl[8][2][1152]; // per-wave dbuf P: 16 rows x 72B

  const int tid = threadIdx.x;
  const int w = tid >> 6, lane = tid & 63;
  const int l15 = lane & 15, l4 = lane >> 4;

  int bid = blockIdx.x;
  int b = (bid & 7) * 32 + (bid >> 3);          // XCD-contiguous logical id
  int g  = (GTOT * b) >> 8;
  int g1 = (GTOT * (b + 1)) >> 8;
  int t = 0;
  while (2 * (t + 1) * (t + 2) <= g) ++t;

  const char* Kb = (const char*)Kh;
  const char* Vb = (const char*)VBg;

#define STAGEKV(KB, BI) do {                                                   \
    _Pragma("unroll")                                                          \
    for (int i_ = 0; i_ < 4; ++i_) {                                           \
      int row_ = w * 4 + i_;                                                   \
      int scol_ = (lane * 16) ^ ((row_ & 7) << 4);                             \
      gload_lds16(Kb + (size_t)((KB) + row_) * 1024 + scol_, Kl[BI] + row_ * 1024); \
    }                                                                          \
    const char* vs_ = Vb + (size_t)(KB) * 1024;                                \
    _Pragma("unroll")                                                          \
    for (int i_ = 0; i_ < 4; ++i_) {                                           \
      int ch_ = w * 4 + i_;                                                    \
      gload_lds16(vs_ + ch_ * 1024 + lane * 16, Vl[BI] + ch_ * 1024);          \
    } } while (0)

// softmax of s0/s1 for kv block KB, P into Pdst (stride-72 rows)
#define SOFTMAX(KB, Pdst) do {                                                 \
    float p0[4], p1[4], mx[4];                                                 \
    int qrb = q0 + w * 16 + l4 * 4;                                            \
    int kc = (KB) + l15;                                                       \
    _Pragma("unroll")                                                          \
    for (int r = 0; r < 4; ++r) {                                              \
      int qr = qrb + r;                                                        \
      float x0 = (kc      <= qr) ? s0[r] : -3.0e38f;                           \
      float x1 = (kc + 16 <= qr) ? s1[r] : -3.0e38f;                           \
      p0[r] = x0; p1[r] = x1;                                                  \
      mx[r] = rowmax16(fmaxf(x0, x1));                                         \
    }                                                                          \
    bool need = (mx[0] > mreg[0] + 8.f) || (mx[1] > mreg[1] + 8.f) ||          \
                (mx[2] > mreg[2] + 8.f) || (mx[3] > mreg[3] + 8.f);            \
    if (__any(need)) {                                                         \
      float alpha[4];                                                          \
      _Pragma("unroll")                                                        \
      for (int r = 0; r < 4; ++r) {                                            \
        float mn = fmaxf(mreg[r], mx[r]);                                      \
        alpha[r] = exp2f((mreg[r] - mn) * L2E);                                \
        lreg[r] *= alpha[r];                                                   \
        mreg[r] = mn;                                                          \
      }                                                                        \
      _Pragma("unroll")                                                        \
      for (int nf = 0; nf < 32; ++nf) {                                        \
        acc[nf][0] *= alpha[0];                                                \
        acc[nf][1] *= alpha[1];                                                \
        acc[nf][2] *= alpha[2];                                                \
        acc[nf][3] *= alpha[3];                                                \
      }                                                                        \
    }                                                                          \
    _Pragma("unroll")                                                          \
    for (int r = 0; r < 4; ++r) {                                              \
      int qr = qrb + r;                                                        \
      p0[r] = (kc      <= qr) ? exp2f((p0[r] - mreg[r]) * L2E) : 0.f;          \
      p1[r] = (kc + 16 <= qr) ? exp2f((p1[r] - mreg[r]) * L2E) : 0.f;          \
    }                                                                          \
    _Pragma("unroll")                                                          \
    for (int r = 0; r < 4; ++r) {                                              \
      int row = l4 * 4 + r;                                                    \
      *(f16*)((Pdst) + row * 72 + l15 * 2)      = (f16)p0[r];                  \
      *(f16*)((Pdst) + row * 72 + 32 + l15 * 2) = (f16)p1[r];                  \
    }                                                                          \
    _Pragma("unroll")                                                          \
    for (int r = 0; r < 4; ++r)                                                \
      lreg[r] += rowsum16(p0[r] + p1[r]);                                      \
  } while (0)

#define QKT(BUF) do {                                                          \
    s0 = (f32x4){0.f, 0.f, 0.f, 0.f};                                          \
    s1 = (f32x4){0.f, 0.f, 0.f, 0.f};                                          \
    _Pragma("unroll")                                                          \
    for (int ks = 0; ks < 16; ++ks) {                                          \
      int off = ks * 64 + l4 * 16;                                             \
      f16x8 kf0 = *(const f16x8*)((BUF) + l15 * 1024 + (off ^ ((l15 & 7) << 4))); \
      s0 = __builtin_amdgcn_mfma_f32_16x16x32_f16(qf[ks], kf0, s0, 0, 0, 0);   \
      f16x8 kf1 = *(const f16x8*)((BUF) + (16 + l15) * 1024 + (off ^ ((l15 & 7) << 4))); \
      s1 = __builtin_amdgcn_mfma_f32_16x16x32_f16(qf[ks], kf1, s1, 0, 0, 0);   \
    } } while (0)

  char* Pw = (char*)Pl + (size_t)w * 2304;

  while (g < g1) {
    int Ct  = 2 * t * (t + 1);
    int Ct1 = 2 * (t + 1) * (t + 2);
    int gend = min(g1, Ct1);
    int n = gend - g;
    int kb0 = (g - Ct) * 32;
    int q0 = t * 128;
    int slot = b + t;

    // Q fragments: rows q0 + w*16 + l15, full D
    f16x8 qf[16];
    {
      const f16* qp = Qh + (size_t)(q0 + w * 16 + l15) * DDIM + l4 * 8;
#pragma unroll
      for (int ks = 0; ks < 16; ++ks) qf[ks] = *(const f16x8*)(qp + ks * 32);
    }
    f32x4 acc[32];
#pragma unroll
    for (int i = 0; i < 32; ++i) acc[i] = (f32x4){0.f, 0.f, 0.f, 0.f};
    float mreg[4], lreg[4];
#pragma unroll
    for (int r = 0; r < 4; ++r) { mreg[r] = -3.0e38f; lreg[r] = 0.f; }
    f32x4 s0, s1;

    // ---- prologue: tile 0 staged+consumed, pipeline primed
    STAGEKV(kb0, 0);
    asm volatile("s_waitcnt vmcnt(0)" ::: "memory");
    __builtin_amdgcn_s_barrier();
    QKT(Kl[0]);
    if (n > 1) STAGEKV(kb0 + 32, 1);
    SOFTMAX(kb0, Pw);                           // -> P[0]
    if (n > 1) asm volatile("s_waitcnt vmcnt(0)" ::: "memory");
    __builtin_amdgcn_s_barrier();

    // ---- steady state: fused QK^T(it) || PV(it-1)
    for (int it = 1; it < n; ++it) {
      const char* KlB = Kl[it & 1];
      const char* VlB = Vl[(it - 1) & 1];
      const char* Pp  = Pw + ((it - 1) & 1) * 1152;
      f16x8 pa = *(const f16x8*)(Pp + l15 * 72 + l4 * 16);
      s0 = (f32x4){0.f, 0.f, 0.f, 0.f};
      s1 = (f32x4){0.f, 0.f, 0.f, 0.f};
      __builtin_amdgcn_s_setprio(1);
#pragma unroll
      for (int ks = 0; ks < 16; ++ks) {
        int off = ks * 64 + l4 * 16;
        f16x8 kf0 = *(const f16x8*)(KlB + l15 * 1024 + (off ^ ((l15 & 7) << 4)));
        s0 = __builtin_amdgcn_mfma_f32_16x16x32_f16(qf[ks], kf0, s0, 0, 0, 0);
        f16x8 vb0 = *(const f16x8*)(VlB + (2 * ks) * 1024 + lane * 16);
        acc[2 * ks] = __builtin_amdgcn_mfma_f32_16x16x32_f16(pa, vb0, acc[2 * ks], 0, 0, 0);
        f16x8 kf1 = *(const f16x8*)(KlB + (16 + l15) * 1024 + (off ^ ((l15 & 7) << 4)));
        s1 = __builtin_amdgcn_mfma_f32_16x16x32_f16(qf[ks], kf1, s1, 0, 0, 0);
        f16x8 vb1 = *(const f16x8*)(VlB + (2 * ks + 1) * 1024 + lane * 16);
        acc[2 * ks + 1] = __builtin_amdgcn_mfma_f32_16x16x32_f16(pa, vb1, acc[2 * ks + 1], 0, 0, 0);
      }
      __builtin_amdgcn_s_setprio(0);
      __builtin_amdgcn_s_barrier();             // all reads of V[(it-1)&1] done

      if (it + 1 < n) STAGEKV(kb0 + (it + 1) * 32, (it + 1) & 1);
      SOFTMAX(kb0 + it * 32, Pw + (it & 1) * 1152);
      if (it + 1 < n) asm volatile("s_waitcnt vmcnt(0)" ::: "memory");
      __builtin_amdgcn_s_barrier();             // staged tile visible
    }

    // ---- drain: PV(n-1)
    {
      const char* VlB = Vl[(n - 1) & 1];
      const char* Pp  = Pw + ((n - 1) & 1) * 1152;
      f16x8 pa = *(const f16x8*)(Pp + l15 * 72 + l4 * 16);
      __builtin_amdgcn_s_setprio(1);
#pragma unroll
      for (int nf = 0; nf < 32; ++nf) {
        f16x8 vb = *(const f16x8*)(VlB + nf * 1024 + lane * 16);
        acc[nf] = __builtin_amdgcn_mfma_f32_16x16x32_f16(pa, vb, acc[nf], 0, 0, 0);
      }
      __builtin_amdgcn_s_setprio(0);
    }
    __builtin_amdgcn_s_barrier();               // before next tile's staging

    // ---- epilogue: all stats in-reg (DPP-reduced => uniform per row group)
    {
      float inv[4];
#pragma unroll
      for (int r = 0; r < 4; ++r) inv[r] = (lreg[r] > 0.f) ? 1.f / lreg[r] : 0.f;
      f16* op = Opart + (size_t)slot * (128 * 512);
      int rowb = w * 16 + l4 * 4;
#pragma unroll
      for (int nf = 0; nf < 32; ++nf) {
        int col = nf * 16 + l15;
#pragma unroll
        for (int r = 0; r < 4; ++r)
          op[(size_t)(rowb + r) * 512 + col] = (f16)(acc[nf][r] * inv[r]);
      }
      if (l15 == 0) {
#pragma unroll
        for (int r = 0; r < 4; ++r) {
          Mpart[slot * 128 + rowb + r] = mreg[r];
          Lpart[slot * 128 + rowb + r] = lreg[r];
        }
      }
      if (tid == 0) TilePart[slot] = t;
    }
    g = gend;
    ++t;
  }
#undef STAGEKV
#undef SOFTMAX
#undef QKT
}

// ---------------- combine partials -> out --------------------------------
__global__ __launch_bounds__(256) void k_reduce(
    const f16* __restrict__ Opart, const float* __restrict__ Mpart,
    const float* __restrict__ Lpart, const int* __restrict__ TilePart,
    float* __restrict__ out) {
  __shared__ int tp[NSLOT];
  __shared__ int sl[16];
  __shared__ int scnt;
  int tid = threadIdx.x;
  int t = blockIdx.x >> 2, rg = blockIdx.x & 3;
  for (int s = tid; s < NSLOT; s += 256) tp[s] = TilePart[s];
  __syncthreads();
  if (tid == 0) {
    int c = 0;
    for (int s = 0; s < NSLOT; ++s)
      if (tp[s] == t && c < 16) sl[c++] = s;
    scnt = c;
  }
  __syncthreads();
  int cnt = scnt;
  int rowIn = rg * 32 + (tid >> 3);
  int row = t * 128 + rowIn;
  int col0 = (tid & 7) * 64;

  float M = -3.0e38f;
  for (int i = 0; i < cnt; ++i) M = fmaxf(M, Mpart[sl[i] * 128 + rowIn]);
  float a[64];
#pragma unroll
  for (int j = 0; j < 64; ++j) a[j] = 0.f;
  float denom = 0.f;
  for (int i = 0; i < cnt; ++i) {
    int s = sl[i];
    float m = Mpart[s * 128 + rowIn];
    float l = Lpart[s * 128 + rowIn];
    float wgt = exp2f((m - M) * L2E) * l;
    denom += wgt;
    const f16* op = Opart + (size_t)s * 65536 + rowIn * 512 + col0;
#pragma unroll
    for (int v = 0; v < 8; ++v) {
      f16x8 x = *(const f16x8*)(op + v * 8);
#pragma unroll
      for (int j = 0; j < 8; ++j) a[v * 8 + j] += wgt * (float)x[j];
    }
  }
  float inv = (denom > 0.f) ? 1.f / denom : 0.f;
  float* o = out + (size_t)row * 512 + col0;
#pragma unroll
  for (int j = 0; j < 64; ++j) o[j] = a[j] * inv;
}

extern "C" void kernel_launch(void* const* d_in, const int* in_sizes, int n_in,
                              void* d_out, int out_size, void* d_ws, size_t ws_size,
                              hipStream_t stream) {
  const float* X  = (const float*)d_in[0];
  const float* Wq = (const float*)d_in[2];
  const float* Wk = (const float*)d_in[3];
  const float* Wv = (const float*)d_in[4];
  float* out = (float*)d_out;

  char* ws = (char*)d_ws;
  f16*   Opart = (f16*)(ws);                               // 40 MiB
  float* Mpart = (float*)(ws + (40u << 20));               // 160 KiB
  float* Lpart = (float*)(ws + (41u << 20));               // 160 KiB
  int*   TileP = (int*)(ws + (42u << 20));                 // 1.25 KiB
  f16* Qh = (f16*)(ws + (43u << 20));                      // 8 MiB (pre-scaled)
  f16* Kh = (f16*)(ws + (51u << 20));                      // 8 MiB
  f16* VB = (f16*)(ws + (59u << 20));                      // 8 MiB packed frags
  f16* Xh = (f16*)(ws + (67u << 20));                      // 8 MiB
  f16* Wh = (f16*)(ws + (75u << 20));                      // 1.5 MiB

  k_convert<<<4864, 256, 0, stream>>>(X, Wq, Wk, Wv, Xh, Wh, TileP);
  dim3 gp(64, 12);
  k_proj<<<gp, 256, 0, stream>>>(Xh, Wh, Qh, Kh, VB);
  k_flash<<<256, 512, 0, stream>>>(Qh, Kh, VB, Opart, Mpart, Lpart, TileP);
  k_reduce<<<256, 256, 0, stream>>>(Opart, Mpart, Lpart, TileP, out);
}

// Round 10
// 242.628 us; speedup vs baseline: 3.2588x; 1.0315x over previous
//
#include <hip/hip_runtime.h>
#include <stdint.h>

typedef _Float16 f16;
typedef _Float16 f16x8 __attribute__((ext_vector_type(8)));
typedef _Float16 f16x4 __attribute__((ext_vector_type(4)));
typedef float f32x4 __attribute__((ext_vector_type(4)));

#define S_TOK 8192
#define DDIM  512
#define L2E   1.44269504088896340736f
#define QSCALE 0.04419417382415922f   // 1/sqrt(512)
#define NSLOT 320
#define GTOT  8320                    // total KVB=32 iterations over all 64 tiles

__device__ __forceinline__ void gload_lds16(const void* g, void* l) {
  __builtin_amdgcn_global_load_lds((const __attribute__((address_space(1))) void*)g,
                                   (__attribute__((address_space(3))) void*)l, 16, 0, 0);
}

// DPP 16-lane (row) reductions — pure VALU, no LDS pipe.
template <int C>
__device__ __forceinline__ float fdpp(float x) {
  return __builtin_bit_cast(float,
      __builtin_amdgcn_update_dpp(0, __builtin_bit_cast(int, x), C, 0xF, 0xF, true));
}
__device__ __forceinline__ float rowmax16(float x) {
  x = fmaxf(x, fdpp<0xB1>(x));    // quad_perm [1,0,3,2]  (xor1)
  x = fmaxf(x, fdpp<0x4E>(x));    // quad_perm [2,3,0,1]  (xor2)
  x = fmaxf(x, fdpp<0x141>(x));   // row_half_mirror
  x = fmaxf(x, fdpp<0x140>(x));   // row_mirror
  return x;
}
__device__ __forceinline__ float rowsum16(float x) {
  x += fdpp<0xB1>(x);
  x += fdpp<0x4E>(x);
  x += fdpp<0x141>(x);
  x += fdpp<0x140>(x);
  return x;
}

// ---------------- convert f32 -> f16 (+ slot-table init) ------------------
__global__ __launch_bounds__(256) void k_convert(
    const float* __restrict__ X, const float* __restrict__ Wq,
    const float* __restrict__ Wk, const float* __restrict__ Wv,
    f16* __restrict__ Xh, f16* __restrict__ Wh, int* __restrict__ tp) {
  const int SD = S_TOK * DDIM;
  const int DD = DDIM * DDIM;
  int gi = blockIdx.x * 256 + threadIdx.x;
  if (gi < NSLOT) tp[gi] = -1;
  int i4 = gi * 4;
  if (i4 < SD) {
    f32x4 v = *(const f32x4*)(X + i4);
    f16x4 h = {(f16)v[0], (f16)v[1], (f16)v[2], (f16)v[3]};
    *(f16x4*)(Xh + i4) = h;
  } else {
    int j = i4 - SD;
    int mat = j >> 18;
    const float* src = (mat == 0) ? Wq : (mat == 1 ? Wk : Wv);
    f32x4 v = *(const f32x4*)(src + (j & (DD - 1)));
    f16x4 h = {(f16)v[0], (f16)v[1], (f16)v[2], (f16)v[3]};
    *(f16x4*)(Wh + j) = h;
  }
}

// ---------------- QKV projection ------------------------------------------
// Q,K row-major (Q pre-scaled). V in packed MFMA-B-frag order (K=32 blocks):
// frag(K=s/32, f=d/16) at byte (K*32+f)*1024 + lane*16 + j*2, holding
// V[K*32 + (lane>>4)*8 + j][f*16 + (lane&15)]
__global__ __launch_bounds__(256) void k_proj(
    const f16* __restrict__ Xh, const f16* __restrict__ Wh,
    f16* __restrict__ Qh, f16* __restrict__ Kh, f16* __restrict__ VB) {
  __shared__ __align__(16) char Al[128 * 128];
  __shared__ __align__(16) char Bl[128 * 128];
  const int tid = threadIdx.x;
  const int w = tid >> 6, lane = tid & 63;
  const int m0 = blockIdx.x * 128;
  const int n0 = blockIdx.y * 128;
  const int wr = (w >> 1) * 64;
  const int wc = (w & 1) * 64;

  f32x4 acc[4][4];
#pragma unroll
  for (int i = 0; i < 4; ++i)
#pragma unroll
    for (int j = 0; j < 4; ++j) acc[i][j] = (f32x4){0.f, 0.f, 0.f, 0.f};

  const char* Xb = (const char*)Xh;
  const char* Wb = (const char*)Wh;

  for (int kb = 0; kb < DDIM; kb += 64) {
    __syncthreads();
#pragma unroll
    for (int i = 0; i < 4; ++i) {
      int ch = w * 4 + i;
      int srow = lane >> 3;
      int scol = ((lane & 7) * 16) ^ (srow << 4);
      gload_lds16(Xb + (size_t)(m0 + ch * 8 + srow) * 1024 + kb * 2 + scol, Al + ch * 1024);
      gload_lds16(Wb + (size_t)(n0 + ch * 8 + srow) * 1024 + kb * 2 + scol, Bl + ch * 1024);
    }
    __syncthreads();
#pragma unroll
    for (int ks = 0; ks < 2; ++ks) {
      f16x8 a[4], b[4];
#pragma unroll
      for (int mf = 0; mf < 4; ++mf) {
        int row = wr + mf * 16 + (lane & 15);
        int col = (ks * 64 + ((lane >> 4) * 16)) ^ ((row & 7) << 4);
        a[mf] = *(const f16x8*)(Al + row * 128 + col);
      }
#pragma unroll
      for (int nf = 0; nf < 4; ++nf) {
        int row = wc + nf * 16 + (lane & 15);
        int col = (ks * 64 + ((lane >> 4) * 16)) ^ ((row & 7) << 4);
        b[nf] = *(const f16x8*)(Bl + row * 128 + col);
      }
#pragma unroll
      for (int mf = 0; mf < 4; ++mf)
#pragma unroll
        for (int nf = 0; nf < 4; ++nf)
          acc[mf][nf] = __builtin_amdgcn_mfma_f32_16x16x32_f16(a[mf], b[nf], acc[mf][nf], 0, 0, 0);
    }
  }
  int mat = n0 >> 9;
  int nbase = n0 & 511;
  if (mat == 2) {
#pragma unroll
    for (int mf = 0; mf < 4; ++mf) {
      int R0 = m0 + wr + mf * 16 + (lane >> 4) * 4;   // 4-aligned token row
      int K = R0 >> 5;
      int lhi = ((R0 >> 3) & 3) * 16;
      int j0 = R0 & 7;                                // 0 or 4
#pragma unroll
      for (int nf = 0; nf < 4; ++nf) {
        int col = nbase + wc + nf * 16 + (lane & 15);
        f16x4 h = {(f16)acc[mf][nf][0], (f16)acc[mf][nf][1],
                   (f16)acc[mf][nf][2], (f16)acc[mf][nf][3]};
        *(f16x4*)((char*)VB + (size_t)(K * 32 + (col >> 4)) * 1024 +
                  (lhi + (col & 15)) * 16 + j0 * 2) = h;
      }
    }
  } else {
    f16* dst = (mat == 0) ? Qh : Kh;
    float scale = (mat == 0) ? QSCALE : 1.0f;
#pragma unroll
    for (int mf = 0; mf < 4; ++mf)
#pragma unroll
      for (int nf = 0; nf < 4; ++nf)
#pragma unroll
        for (int r = 0; r < 4; ++r) {
          int row = m0 + wr + mf * 16 + (lane >> 4) * 4 + r;
          int col = nbase + wc + nf * 16 + (lane & 15);
          dst[(size_t)row * DDIM + col] = (f16)(acc[mf][nf][r] * scale);
        }
  }
}

// ---------------- causal flash attention, v10 ------------------------------
// R9 structure with ONE barrier/iter and long-distance staging:
//   PV(it-1) -> vmcnt(0)[stage(it), issued a full phase ago] -> barrier ->
//   STAGE(it+1) -> QK^T(it) -> softmax(it) -> P[it&1]
// P wave-private dbuf (no publication barrier needed). Stage->wait gap is
// ~one full iteration, covering HBM latency + transfer (counted-vmcnt idea).
__global__ __launch_bounds__(512, 2) void k_flash(
    const f16* __restrict__ Qh, const f16* __restrict__ Kh,
    const f16* __restrict__ VBg, f16* __restrict__ Opart,
    float* __restrict__ Mpart, float* __restrict__ Lpart,
    int* __restrict__ TilePart) {
  __shared__ __align__(16) char Kl[2][32768];   // K tile [32][512 f16] swizzled
  __shared__ __align__(16) char Vl[2][32768];   // V frag-packed [32 frags][1KB]
  __shared__ __align__(16) char Pl[8][2][1152]; // per-wave dbuf P: 16 rows x 72B

  const int tid = threadIdx.x;
  const int w = tid >> 6, lane = tid & 63;
  const int l15 = lane & 15, l4 = lane >> 4;

  int bid = blockIdx.x;
  int b = (bid & 7) * 32 + (bid >> 3);          // XCD-contiguous logical id
  int g  = (GTOT * b) >> 8;
  int g1 = (GTOT * (b + 1)) >> 8;
  int t = 0;
  while (2 * (t + 1) * (t + 2) <= g) ++t;

  const char* Kb = (const char*)Kh;
  const char* Vb = (const char*)VBg;

#define STAGEKV(KB, BI) do {                                                   \
    _Pragma("unroll")                                                          \
    for (int i_ = 0; i_ < 4; ++i_) {                                           \
      int row_ = w * 4 + i_;                                                   \
      int scol_ = (lane * 16) ^ ((row_ & 7) << 4);                             \
      gload_lds16(Kb + (size_t)((KB) + row_) * 1024 + scol_, Kl[BI] + row_ * 1024); \
    }                                                                          \
    const char* vs_ = Vb + (size_t)(KB) * 1024;                                \
    _Pragma("unroll")                                                          \
    for (int i_ = 0; i_ < 4; ++i_) {                                           \
      int ch_ = w * 4 + i_;                                                    \
      gload_lds16(vs_ + ch_ * 1024 + lane * 16, Vl[BI] + ch_ * 1024);          \
    } } while (0)

// softmax of s0/s1 for kv block KB, P into Pdst (stride-72 rows)
#define SOFTMAX(KB, Pdst) do {                                                 \
    float p0[4], p1[4], mx[4];                                                 \
    int qrb = q0 + w * 16 + l4 * 4;                                            \
    int kc = (KB) + l15;                                                       \
    _Pragma("unroll")                                                          \
    for (int r = 0; r < 4; ++r) {                                              \
      int qr = qrb + r;                                                        \
      float x0 = (kc      <= qr) ? s0[r] : -3.0e38f;                           \
      float x1 = (kc + 16 <= qr) ? s1[r] : -3.0e38f;                           \
      p0[r] = x0; p1[r] = x1;                                                  \
      mx[r] = rowmax16(fmaxf(x0, x1));                                         \
    }                                                                          \
    bool need = (mx[0] > mreg[0] + 8.f) || (mx[1] > mreg[1] + 8.f) ||          \
                (mx[2] > mreg[2] + 8.f) || (mx[3] > mreg[3] + 8.f);            \
    if (__any(need)) {                                                         \
      float alpha[4];                                                          \
      _Pragma("unroll")                                                        \
      for (int r = 0; r < 4; ++r) {                                            \
        float mn = fmaxf(mreg[r], mx[r]);                                      \
        alpha[r] = exp2f((mreg[r] - mn) * L2E);                                \
        lreg[r] *= alpha[r];                                                   \
        mreg[r] = mn;                                                          \
      }                                                                        \
      _Pragma("unroll")                                                        \
      for (int nf = 0; nf < 32; ++nf) {                                        \
        acc[nf][0] *= alpha[0];                                                \
        acc[nf][1] *= alpha[1];                                                \
        acc[nf][2] *= alpha[2];                                                \
        acc[nf][3] *= alpha[3];                                                \
      }                                                                        \
    }                                                                          \
    _Pragma("unroll")                                                          \
    for (int r = 0; r < 4; ++r) {                                              \
      int qr = qrb + r;                                                        \
      p0[r] = (kc      <= qr) ? exp2f((p0[r] - mreg[r]) * L2E) : 0.f;          \
      p1[r] = (kc + 16 <= qr) ? exp2f((p1[r] - mreg[r]) * L2E) : 0.f;          \
    }                                                                          \
    _Pragma("unroll")                                                          \
    for (int r = 0; r < 4; ++r) {                                              \
      int row = l4 * 4 + r;                                                    \
      *(f16*)((Pdst) + row * 72 + l15 * 2)      = (f16)p0[r];                  \
      *(f16*)((Pdst) + row * 72 + 32 + l15 * 2) = (f16)p1[r];                  \
    }                                                                          \
    _Pragma("unroll")                                                          \
    for (int r = 0; r < 4; ++r)                                                \
      lreg[r] += rowsum16(p0[r] + p1[r]);                                      \
  } while (0)

#define QKT(BUF) do {                                                          \
    s0 = (f32x4){0.f, 0.f, 0.f, 0.f};                                          \
    s1 = (f32x4){0.f, 0.f, 0.f, 0.f};                                          \
    __builtin_amdgcn_s_setprio(1);                                             \
    _Pragma("unroll")                                                          \
    for (int ks = 0; ks < 16; ++ks) {                                          \
      int off = ks * 64 + l4 * 16;                                             \
      f16x8 kf0 = *(const f16x8*)((BUF) + l15 * 1024 + (off ^ ((l15 & 7) << 4))); \
      s0 = __builtin_amdgcn_mfma_f32_16x16x32_f16(qf[ks], kf0, s0, 0, 0, 0);   \
      f16x8 kf1 = *(const f16x8*)((BUF) + (16 + l15) * 1024 + (off ^ ((l15 & 7) << 4))); \
      s1 = __builtin_amdgcn_mfma_f32_16x16x32_f16(qf[ks], kf1, s1, 0, 0, 0);   \
    }                                                                          \
    __builtin_amdgcn_s_setprio(0); } while (0)

#define PV(BI) do {                                                            \
    const char* VlB_ = Vl[BI];                                                 \
    const char* Pp_ = Pw + (BI) * 1152;                                        \
    f16x8 pa_ = *(const f16x8*)(Pp_ + l15 * 72 + l4 * 16);                     \
    __builtin_amdgcn_s_setprio(1);                                             \
    _Pragma("unroll")                                                          \
    for (int nf = 0; nf < 32; ++nf) {                                          \
      f16x8 vb_ = *(const f16x8*)(VlB_ + nf * 1024 + lane * 16);               \
      acc[nf] = __builtin_amdgcn_mfma_f32_16x16x32_f16(pa_, vb_, acc[nf], 0, 0, 0); \
    }                                                                          \
    __builtin_amdgcn_s_setprio(0); } while (0)

  char* Pw = (char*)Pl + (size_t)w * 2304;

  while (g < g1) {
    int Ct  = 2 * t * (t + 1);
    int Ct1 = 2 * (t + 1) * (t + 2);
    int gend = min(g1, Ct1);
    int n = gend - g;
    int kb0 = (g - Ct) * 32;
    int q0 = t * 128;
    int slot = b + t;

    // Q fragments: rows q0 + w*16 + l15, full D
    f16x8 qf[16];
    {
      const f16* qp = Qh + (size_t)(q0 + w * 16 + l15) * DDIM + l4 * 8;
#pragma unroll
      for (int ks = 0; ks < 16; ++ks) qf[ks] = *(const f16x8*)(qp + ks * 32);
    }
    f32x4 acc[32];
#pragma unroll
    for (int i = 0; i < 32; ++i) acc[i] = (f32x4){0.f, 0.f, 0.f, 0.f};
    float mreg[4], lreg[4];
#pragma unroll
    for (int r = 0; r < 4; ++r) { mreg[r] = -3.0e38f; lreg[r] = 0.f; }
    f32x4 s0, s1;

    // ---- prologue: stage(0) waited, stage(1) in flight across QKT+SM
    STAGEKV(kb0, 0);
    asm volatile("s_waitcnt vmcnt(0)" ::: "memory");
    __builtin_amdgcn_s_barrier();
    if (n > 1) STAGEKV(kb0 + 32, 1);
    QKT(Kl[0]);
    SOFTMAX(kb0, Pw);                           // -> P[0]

    // ---- steady state: one barrier per iteration
    for (int it = 1; it < n; ++it) {
      PV((it - 1) & 1);                         // V(it-1), P(it-1): own-wave data
      asm volatile("s_waitcnt vmcnt(0)" ::: "memory");  // stage(it) landed (issued ~1 iter ago)
      __builtin_amdgcn_s_barrier();             // publish K(it),V(it); K/V(it-1) reads done
      if (it + 1 < n) STAGEKV(kb0 + (it + 1) * 32, (it + 1) & 1);
      QKT(Kl[it & 1]);
      SOFTMAX(kb0 + it * 32, Pw + (it & 1) * 1152);
    }

    // ---- drain: PV(n-1)
    PV((n - 1) & 1);
    __builtin_amdgcn_s_barrier();               // before next tile's staging

    // ---- epilogue: all stats in-reg (DPP-reduced => uniform per row group)
    {
      float inv[4];
#pragma unroll
      for (int r = 0; r < 4; ++r) inv[r] = (lreg[r] > 0.f) ? 1.f / lreg[r] : 0.f;
      f16* op = Opart + (size_t)slot * (128 * 512);
      int rowb = w * 16 + l4 * 4;
#pragma unroll
      for (int nf = 0; nf < 32; ++nf) {
        int col = nf * 16 + l15;
#pragma unroll
        for (int r = 0; r < 4; ++r)
          op[(size_t)(rowb + r) * 512 + col] = (f16)(acc[nf][r] * inv[r]);
      }
      if (l15 == 0) {
#pragma unroll
        for (int r = 0; r < 4; ++r) {
          Mpart[slot * 128 + rowb + r] = mreg[r];
          Lpart[slot * 128 + rowb + r] = lreg[r];
        }
      }
      if (tid == 0) TilePart[slot] = t;
    }
    g = gend;
    ++t;
  }
#undef STAGEKV
#undef SOFTMAX
#undef QKT
#undef PV
}

// ---------------- combine partials -> out --------------------------------
__global__ __launch_bounds__(256) void k_reduce(
    const f16* __restrict__ Opart, const float* __restrict__ Mpart,
    const float* __restrict__ Lpart, const int* __restrict__ TilePart,
    float* __restrict__ out) {
  __shared__ int tp[NSLOT];
  __shared__ int sl[16];
  __shared__ int scnt;
  int tid = threadIdx.x;
  int t = blockIdx.x >> 2, rg = blockIdx.x & 3;
  for (int s = tid; s < NSLOT; s += 256) tp[s] = TilePart[s];
  __syncthreads();
  if (tid == 0) {
    int c = 0;
    for (int s = 0; s < NSLOT; ++s)
      if (tp[s] == t && c < 16) sl[c++] = s;
    scnt = c;
  }
  __syncthreads();
  int cnt = scnt;
  int rowIn = rg * 32 + (tid >> 3);
  int row = t * 128 + rowIn;
  int col0 = (tid & 7) * 64;

  float M = -3.0e38f;
  for (int i = 0; i < cnt; ++i) M = fmaxf(M, Mpart[sl[i] * 128 + rowIn]);
  float a[64];
#pragma unroll
  for (int j = 0; j < 64; ++j) a[j] = 0.f;
  float denom = 0.f;
  for (int i = 0; i < cnt; ++i) {
    int s = sl[i];
    float m = Mpart[s * 128 + rowIn];
    float l = Lpart[s * 128 + rowIn];
    float wgt = exp2f((m - M) * L2E) * l;
    denom += wgt;
    const f16* op = Opart + (size_t)s * 65536 + rowIn * 512 + col0;
#pragma unroll
    for (int v = 0; v < 8; ++v) {
      f16x8 x = *(const f16x8*)(op + v * 8);
#pragma unroll
      for (int j = 0; j < 8; ++j) a[v * 8 + j] += wgt * (float)x[j];
    }
  }
  float inv = (denom > 0.f) ? 1.f / denom : 0.f;
  float* o = out + (size_t)row * 512 + col0;
#pragma unroll
  for (int j = 0; j < 64; ++j) o[j] = a[j] * inv;
}

extern "C" void kernel_launch(void* const* d_in, const int* in_sizes, int n_in,
                              void* d_out, int out_size, void* d_ws, size_t ws_size,
                              hipStream_t stream) {
  const float* X  = (const float*)d_in[0];
  const float* Wq = (const float*)d_in[2];
  const float* Wk = (const float*)d_in[3];
  const float* Wv = (const float*)d_in[4];
  float* out = (float*)d_out;

  char* ws = (char*)d_ws;
  f16*   Opart = (f16*)(ws);                               // 40 MiB
  float* Mpart = (float*)(ws + (40u << 20));               // 160 KiB
  float* Lpart = (float*)(ws + (41u << 20));               // 160 KiB
  int*   TileP = (int*)(ws + (42u << 20));                 // 1.25 KiB
  f16* Qh = (f16*)(ws + (43u << 20));                      // 8 MiB (pre-scaled)
  f16* Kh = (f16*)(ws + (51u << 20));                      // 8 MiB
  f16* VB = (f16*)(ws + (59u << 20));                      // 8 MiB packed frags
  f16* Xh = (f16*)(ws + (67u << 20));                      // 8 MiB
  f16* Wh = (f16*)(ws + (75u << 20));                      // 1.5 MiB

  k_convert<<<4864, 256, 0, stream>>>(X, Wq, Wk, Wv, Xh, Wh, TileP);
  dim3 gp(64, 12);
  k_proj<<<gp, 256, 0, stream>>>(Xh, Wh, Qh, Kh, VB);
  k_flash<<<256, 512, 0, stream>>>(Qh, Kh, VB, Opart, Mpart, Lpart, TileP);
  k_reduce<<<256, 256, 0, stream>>>(Opart, Mpart, Lpart, TileP, out);
}

// Round 11
// 213.060 us; speedup vs baseline: 3.7111x; 1.1388x over previous
//
#include <hip/hip_runtime.h>
#include <stdint.h>

typedef _Float16 f16;
typedef _Float16 f16x8 __attribute__((ext_vector_type(8)));
typedef _Float16 f16x4 __attribute__((ext_vector_type(4)));
typedef float f32x4 __attribute__((ext_vector_type(4)));

#define S_TOK 8192
#define DDIM  512
#define L2E   1.44269504088896340736f
#define QSCALE 0.04419417382415922f   // 1/sqrt(512)
#define NSLOT 320
#define GTOT  8320                    // total KVB=32 iterations over all 64 tiles

__device__ __forceinline__ void gload_lds16(const void* g, void* l) {
  __builtin_amdgcn_global_load_lds((const __attribute__((address_space(1))) void*)g,
                                   (__attribute__((address_space(3))) void*)l, 16, 0, 0);
}

// DPP 16-lane (row) reductions — pure VALU, no LDS pipe.
template <int C>
__device__ __forceinline__ float fdpp(float x) {
  return __builtin_bit_cast(float,
      __builtin_amdgcn_update_dpp(0, __builtin_bit_cast(int, x), C, 0xF, 0xF, true));
}
__device__ __forceinline__ float rowmax16(float x) {
  x = fmaxf(x, fdpp<0xB1>(x));    // quad_perm [1,0,3,2]  (xor1)
  x = fmaxf(x, fdpp<0x4E>(x));    // quad_perm [2,3,0,1]  (xor2)
  x = fmaxf(x, fdpp<0x141>(x));   // row_half_mirror
  x = fmaxf(x, fdpp<0x140>(x));   // row_mirror
  return x;
}
__device__ __forceinline__ float rowsum16(float x) {
  x += fdpp<0xB1>(x);
  x += fdpp<0x4E>(x);
  x += fdpp<0x141>(x);
  x += fdpp<0x140>(x);
  return x;
}

// ---------------- convert f32 -> f16 (+ slot-table init) ------------------
__global__ __launch_bounds__(256) void k_convert(
    const float* __restrict__ X, const float* __restrict__ Wq,
    const float* __restrict__ Wk, const float* __restrict__ Wv,
    f16* __restrict__ Xh, f16* __restrict__ Wh, int* __restrict__ tp) {
  const int SD = S_TOK * DDIM;
  const int DD = DDIM * DDIM;
  int gi = blockIdx.x * 256 + threadIdx.x;
  if (gi < NSLOT) tp[gi] = -1;
  int i4 = gi * 4;
  if (i4 < SD) {
    f32x4 v = *(const f32x4*)(X + i4);
    f16x4 h = {(f16)v[0], (f16)v[1], (f16)v[2], (f16)v[3]};
    *(f16x4*)(Xh + i4) = h;
  } else {
    int j = i4 - SD;
    int mat = j >> 18;
    const float* src = (mat == 0) ? Wq : (mat == 1 ? Wk : Wv);
    f32x4 v = *(const f32x4*)(src + (j & (DD - 1)));
    f16x4 h = {(f16)v[0], (f16)v[1], (f16)v[2], (f16)v[3]};
    *(f16x4*)(Wh + j) = h;
  }
}

// ---------------- QKV projection ------------------------------------------
// Q row-major (pre-scaled).
// K in QKT-B-frag order: per 32-token tile (32KB), frag(half,ks) is 1KB at
//   byte (tile*32 + half*16 + ks)*1024 ... precisely:
//   tile*32768 + half*16384 + ks*1024 + lane*16 + j*2 holds
//   K[tile*32 + half*16 + (lane&15)][ks*32 + (lane>>4)*8 + j]
// V in PV-B-frag order (K=32 blocks): frag(K=s/32, f=d/16) at byte
//   (K*32+f)*1024 + lane*16 + j*2 holds V[K*32+(lane>>4)*8+j][f*16+(lane&15)]
__global__ __launch_bounds__(256) void k_proj(
    const f16* __restrict__ Xh, const f16* __restrict__ Wh,
    f16* __restrict__ Qh, f16* __restrict__ KB, f16* __restrict__ VB) {
  __shared__ __align__(16) char Al[128 * 128];
  __shared__ __align__(16) char Bl[128 * 128];
  const int tid = threadIdx.x;
  const int w = tid >> 6, lane = tid & 63;
  const int m0 = blockIdx.x * 128;
  const int n0 = blockIdx.y * 128;
  const int wr = (w >> 1) * 64;
  const int wc = (w & 1) * 64;

  f32x4 acc[4][4];
#pragma unroll
  for (int i = 0; i < 4; ++i)
#pragma unroll
    for (int j = 0; j < 4; ++j) acc[i][j] = (f32x4){0.f, 0.f, 0.f, 0.f};

  const char* Xb = (const char*)Xh;
  const char* Wb = (const char*)Wh;

  for (int kb = 0; kb < DDIM; kb += 64) {
    __syncthreads();
#pragma unroll
    for (int i = 0; i < 4; ++i) {
      int ch = w * 4 + i;
      int srow = lane >> 3;
      int scol = ((lane & 7) * 16) ^ (srow << 4);
      gload_lds16(Xb + (size_t)(m0 + ch * 8 + srow) * 1024 + kb * 2 + scol, Al + ch * 1024);
      gload_lds16(Wb + (size_t)(n0 + ch * 8 + srow) * 1024 + kb * 2 + scol, Bl + ch * 1024);
    }
    __syncthreads();
#pragma unroll
    for (int ks = 0; ks < 2; ++ks) {
      f16x8 a[4], b[4];
#pragma unroll
      for (int mf = 0; mf < 4; ++mf) {
        int row = wr + mf * 16 + (lane & 15);
        int col = (ks * 64 + ((lane >> 4) * 16)) ^ ((row & 7) << 4);
        a[mf] = *(const f16x8*)(Al + row * 128 + col);
      }
#pragma unroll
      for (int nf = 0; nf < 4; ++nf) {
        int row = wc + nf * 16 + (lane & 15);
        int col = (ks * 64 + ((lane >> 4) * 16)) ^ ((row & 7) << 4);
        b[nf] = *(const f16x8*)(Bl + row * 128 + col);
      }
#pragma unroll
      for (int mf = 0; mf < 4; ++mf)
#pragma unroll
        for (int nf = 0; nf < 4; ++nf)
          acc[mf][nf] = __builtin_amdgcn_mfma_f32_16x16x32_f16(a[mf], b[nf], acc[mf][nf], 0, 0, 0);
    }
  }
  int mat = n0 >> 9;
  int nbase = n0 & 511;
  if (mat == 2) {
#pragma unroll
    for (int mf = 0; mf < 4; ++mf) {
      int R0 = m0 + wr + mf * 16 + (lane >> 4) * 4;   // 4-aligned token row
      int K = R0 >> 5;
      int lhi = ((R0 >> 3) & 3) * 16;
      int j0 = R0 & 7;                                // 0 or 4
#pragma unroll
      for (int nf = 0; nf < 4; ++nf) {
        int col = nbase + wc + nf * 16 + (lane & 15);
        f16x4 h = {(f16)acc[mf][nf][0], (f16)acc[mf][nf][1],
                   (f16)acc[mf][nf][2], (f16)acc[mf][nf][3]};
        *(f16x4*)((char*)VB + (size_t)(K * 32 + (col >> 4)) * 1024 +
                  (lhi + (col & 15)) * 16 + j0 * 2) = h;
      }
    }
  } else if (mat == 1) {
    // K -> QKT-B-frag order (scattered f16 stores; lanes of a row write
    // 2B at 2..16B spacing — one-time 8MB traffic)
#pragma unroll
    for (int mf = 0; mf < 4; ++mf)
#pragma unroll
      for (int nf = 0; nf < 4; ++nf)
#pragma unroll
        for (int r = 0; r < 4; ++r) {
          int token = m0 + wr + mf * 16 + (lane >> 4) * 4 + r;
          int d = nbase + wc + nf * 16 + (lane & 15);
          size_t byte = (size_t)(token >> 5) * 32768 + (size_t)((token >> 4) & 1) * 16384
                      + (size_t)(d >> 5) * 1024
                      + (token & 15) * 16 + ((d >> 3) & 3) * 256 + (d & 7) * 2;
          *(f16*)((char*)KB + byte) = (f16)acc[mf][nf][r];
        }
  } else {
    float scale = QSCALE;
#pragma unroll
    for (int mf = 0; mf < 4; ++mf)
#pragma unroll
      for (int nf = 0; nf < 4; ++nf)
#pragma unroll
        for (int r = 0; r < 4; ++r) {
          int row = m0 + wr + mf * 16 + (lane >> 4) * 4 + r;
          int col = nbase + wc + nf * 16 + (lane & 15);
          Qh[(size_t)row * DDIM + col] = (f16)(acc[mf][nf][r] * scale);
        }
  }
}

// ---------------- causal flash attention, v11 ------------------------------
// R10 structure (one barrier/iter, long-distance staging, P wave-private
// dbuf) with K frag-packed in global: staging is a linear copy and every
// QKT ds_read is base + compile-time immediate (no per-read VALU, no XOR).
__global__ __launch_bounds__(512, 2) void k_flash(
    const f16* __restrict__ Qh, const f16* __restrict__ KBg,
    const f16* __restrict__ VBg, f16* __restrict__ Opart,
    float* __restrict__ Mpart, float* __restrict__ Lpart,
    int* __restrict__ TilePart) {
  __shared__ __align__(16) char Kl[2][32768];   // K tile, frag-packed (linear)
  __shared__ __align__(16) char Vl[2][32768];   // V frag-packed [32 frags][1KB]
  __shared__ __align__(16) char Pl[8][2][1152]; // per-wave dbuf P: 16 rows x 72B

  const int tid = threadIdx.x;
  const int w = tid >> 6, lane = tid & 63;
  const int l15 = lane & 15, l4 = lane >> 4;

  int bid = blockIdx.x;
  int b = (bid & 7) * 32 + (bid >> 3);          // XCD-contiguous logical id
  int g  = (GTOT * b) >> 8;
  int g1 = (GTOT * (b + 1)) >> 8;
  int t = 0;
  while (2 * (t + 1) * (t + 2) <= g) ++t;

  const char* Kb = (const char*)KBg;
  const char* Vb = (const char*)VBg;

#define STAGEKV(KB_, BI) do {                                                  \
    const char* ks_ = Kb + (size_t)((KB_) >> 5) * 32768;                       \
    _Pragma("unroll")                                                          \
    for (int i_ = 0; i_ < 4; ++i_) {                                           \
      int ch_ = w * 4 + i_;                                                    \
      gload_lds16(ks_ + ch_ * 1024 + lane * 16, Kl[BI] + ch_ * 1024);          \
    }                                                                          \
    const char* vs_ = Vb + (size_t)(KB_) * 1024;                               \
    _Pragma("unroll")                                                          \
    for (int i_ = 0; i_ < 4; ++i_) {                                           \
      int ch_ = w * 4 + i_;                                                    \
      gload_lds16(vs_ + ch_ * 1024 + lane * 16, Vl[BI] + ch_ * 1024);          \
    } } while (0)

// softmax of s0/s1 for kv block KB_, P into Pdst (stride-72 rows)
#define SOFTMAX(KB_, Pdst) do {                                                \
    float p0[4], p1[4], mx[4];                                                 \
    int qrb = q0 + w * 16 + l4 * 4;                                            \
    int kc = (KB_) + l15;                                                      \
    _Pragma("unroll")                                                          \
    for (int r = 0; r < 4; ++r) {                                              \
      int qr = qrb + r;                                                        \
      float x0 = (kc      <= qr) ? s0[r] : -3.0e38f;                           \
      float x1 = (kc + 16 <= qr) ? s1[r] : -3.0e38f;                           \
      p0[r] = x0; p1[r] = x1;                                                  \
      mx[r] = rowmax16(fmaxf(x0, x1));                                         \
    }                                                                          \
    bool need = (mx[0] > mreg[0] + 8.f) || (mx[1] > mreg[1] + 8.f) ||          \
                (mx[2] > mreg[2] + 8.f) || (mx[3] > mreg[3] + 8.f);            \
    if (__any(need)) {                                                         \
      float alpha[4];                                                          \
      _Pragma("unroll")                                                        \
      for (int r = 0; r < 4; ++r) {                                            \
        float mn = fmaxf(mreg[r], mx[r]);                                      \
        alpha[r] = exp2f((mreg[r] - mn) * L2E);                                \
        lreg[r] *= alpha[r];                                                   \
        mreg[r] = mn;                                                          \
      }                                                                        \
      _Pragma("unroll")                                                        \
      for (int nf = 0; nf < 32; ++nf) {                                        \
        acc[nf][0] *= alpha[0];                                                \
        acc[nf][1] *= alpha[1];                                                \
        acc[nf][2] *= alpha[2];                                                \
        acc[nf][3] *= alpha[3];                                                \
      }                                                                        \
    }                                                                          \
    _Pragma("unroll")                                                          \
    for (int r = 0; r < 4; ++r) {                                              \
      int qr = qrb + r;                                                        \
      p0[r] = (kc      <= qr) ? exp2f((p0[r] - mreg[r]) * L2E) : 0.f;          \
      p1[r] = (kc + 16 <= qr) ? exp2f((p1[r] - mreg[r]) * L2E) : 0.f;          \
    }                                                                          \
    _Pragma("unroll")                                                          \
    for (int r = 0; r < 4; ++r) {                                              \
      int row = l4 * 4 + r;                                                    \
      *(f16*)((Pdst) + row * 72 + l15 * 2)      = (f16)p0[r];                  \
      *(f16*)((Pdst) + row * 72 + 32 + l15 * 2) = (f16)p1[r];                  \
    }                                                                          \
    _Pragma("unroll")                                                          \
    for (int r = 0; r < 4; ++r)                                                \
      lreg[r] += rowsum16(p0[r] + p1[r]);                                      \
  } while (0)

// QKT: frag-packed K -> one base register, all offsets immediate
#define QKT(BUF) do {                                                          \
    s0 = (f32x4){0.f, 0.f, 0.f, 0.f};                                          \
    s1 = (f32x4){0.f, 0.f, 0.f, 0.f};                                          \
    const char* kp_ = (BUF) + lane * 16;                                       \
    __builtin_amdgcn_s_setprio(1);                                             \
    _Pragma("unroll")                                                          \
    for (int ks = 0; ks < 16; ++ks) {                                          \
      f16x8 kf0 = *(const f16x8*)(kp_ + ks * 1024);                            \
      s0 = __builtin_amdgcn_mfma_f32_16x16x32_f16(qf[ks], kf0, s0, 0, 0, 0);   \
      f16x8 kf1 = *(const f16x8*)(kp_ + 16384 + ks * 1024);                    \
      s1 = __builtin_amdgcn_mfma_f32_16x16x32_f16(qf[ks], kf1, s1, 0, 0, 0);   \
    }                                                                          \
    __builtin_amdgcn_s_setprio(0); } while (0)

#define PV(BI) do {                                                            \
    const char* VlB_ = Vl[BI] + lane * 16;                                     \
    const char* Pp_ = Pw + (BI) * 1152;                                        \
    f16x8 pa_ = *(const f16x8*)(Pp_ + l15 * 72 + l4 * 16);                     \
    __builtin_amdgcn_s_setprio(1);                                             \
    _Pragma("unroll")                                                          \
    for (int nf = 0; nf < 32; ++nf) {                                          \
      f16x8 vb_ = *(const f16x8*)(VlB_ + nf * 1024);                           \
      acc[nf] = __builtin_amdgcn_mfma_f32_16x16x32_f16(pa_, vb_, acc[nf], 0, 0, 0); \
    }                                                                          \
    __builtin_amdgcn_s_setprio(0); } while (0)

  char* Pw = (char*)Pl + (size_t)w * 2304;

  while (g < g1) {
    int Ct  = 2 * t * (t + 1);
    int Ct1 = 2 * (t + 1) * (t + 2);
    int gend = min(g1, Ct1);
    int n = gend - g;
    int kb0 = (g - Ct) * 32;
    int q0 = t * 128;
    int slot = b + t;

    // Q fragments: rows q0 + w*16 + l15, full D
    f16x8 qf[16];
    {
      const f16* qp = Qh + (size_t)(q0 + w * 16 + l15) * DDIM + l4 * 8;
#pragma unroll
      for (int ks = 0; ks < 16; ++ks) qf[ks] = *(const f16x8*)(qp + ks * 32);
    }
    f32x4 acc[32];
#pragma unroll
    for (int i = 0; i < 32; ++i) acc[i] = (f32x4){0.f, 0.f, 0.f, 0.f};
    float mreg[4], lreg[4];
#pragma unroll
    for (int r = 0; r < 4; ++r) { mreg[r] = -3.0e38f; lreg[r] = 0.f; }
    f32x4 s0, s1;

    // ---- prologue: stage(0) waited, stage(1) in flight across QKT+SM
    STAGEKV(kb0, 0);
    asm volatile("s_waitcnt vmcnt(0)" ::: "memory");
    __builtin_amdgcn_s_barrier();
    if (n > 1) STAGEKV(kb0 + 32, 1);
    QKT(Kl[0]);
    SOFTMAX(kb0, Pw);                           // -> P[0]

    // ---- steady state: one barrier per iteration
    for (int it = 1; it < n; ++it) {
      PV((it - 1) & 1);                         // V(it-1), P(it-1): own-wave data
      asm volatile("s_waitcnt vmcnt(0)" ::: "memory");  // stage(it) landed (issued ~1 iter ago)
      __builtin_amdgcn_s_barrier();             // publish K(it),V(it); K/V(it-1) reads done
      if (it + 1 < n) STAGEKV(kb0 + (it + 1) * 32, (it + 1) & 1);
      QKT(Kl[it & 1]);
      SOFTMAX(kb0 + it * 32, Pw + (it & 1) * 1152);
    }

    // ---- drain: PV(n-1)
    PV((n - 1) & 1);
    __builtin_amdgcn_s_barrier();               // before next tile's staging

    // ---- epilogue: all stats in-reg (DPP-reduced => uniform per row group)
    {
      float inv[4];
#pragma unroll
      for (int r = 0; r < 4; ++r) inv[r] = (lreg[r] > 0.f) ? 1.f / lreg[r] : 0.f;
      f16* op = Opart + (size_t)slot * (128 * 512);
      int rowb = w * 16 + l4 * 4;
#pragma unroll
      for (int nf = 0; nf < 32; ++nf) {
        int col = nf * 16 + l15;
#pragma unroll
        for (int r = 0; r < 4; ++r)
          op[(size_t)(rowb + r) * 512 + col] = (f16)(acc[nf][r] * inv[r]);
      }
      if (l15 == 0) {
#pragma unroll
        for (int r = 0; r < 4; ++r) {
          Mpart[slot * 128 + rowb + r] = mreg[r];
          Lpart[slot * 128 + rowb + r] = lreg[r];
        }
      }
      if (tid == 0) TilePart[slot] = t;
    }
    g = gend;
    ++t;
  }
#undef STAGEKV
#undef SOFTMAX
#undef QKT
#undef PV
}

// ---------------- combine partials -> out --------------------------------
__global__ __launch_bounds__(256) void k_reduce(
    const f16* __restrict__ Opart, const float* __restrict__ Mpart,
    const float* __restrict__ Lpart, const int* __restrict__ TilePart,
    float* __restrict__ out) {
  __shared__ int tp[NSLOT];
  __shared__ int sl[16];
  __shared__ int scnt;
  int tid = threadIdx.x;
  int t = blockIdx.x >> 2, rg = blockIdx.x & 3;
  for (int s = tid; s < NSLOT; s += 256) tp[s] = TilePart[s];
  __syncthreads();
  if (tid == 0) {
    int c = 0;
    for (int s = 0; s < NSLOT; ++s)
      if (tp[s] == t && c < 16) sl[c++] = s;
    scnt = c;
  }
  __syncthreads();
  int cnt = scnt;
  int rowIn = rg * 32 + (tid >> 3);
  int row = t * 128 + rowIn;
  int col0 = (tid & 7) * 64;

  float M = -3.0e38f;
  for (int i = 0; i < cnt; ++i) M = fmaxf(M, Mpart[sl[i] * 128 + rowIn]);
  float a[64];
#pragma unroll
  for (int j = 0; j < 64; ++j) a[j] = 0.f;
  float denom = 0.f;
  for (int i = 0; i < cnt; ++i) {
    int s = sl[i];
    float m = Mpart[s * 128 + rowIn];
    float l = Lpart[s * 128 + rowIn];
    float wgt = exp2f((m - M) * L2E) * l;
    denom += wgt;
    const f16* op = Opart + (size_t)s * 65536 + rowIn * 512 + col0;
#pragma unroll
    for (int v = 0; v < 8; ++v) {
      f16x8 x = *(const f16x8*)(op + v * 8);
#pragma unroll
      for (int j = 0; j < 8; ++j) a[v * 8 + j] += wgt * (float)x[j];
    }
  }
  float inv = (denom > 0.f) ? 1.f / denom : 0.f;
  float* o = out + (size_t)row * 512 + col0;
#pragma unroll
  for (int j = 0; j < 64; ++j) o[j] = a[j] * inv;
}

extern "C" void kernel_launch(void* const* d_in, const int* in_sizes, int n_in,
                              void* d_out, int out_size, void* d_ws, size_t ws_size,
                              hipStream_t stream) {
  const float* X  = (const float*)d_in[0];
  const float* Wq = (const float*)d_in[2];
  const float* Wk = (const float*)d_in[3];
  const float* Wv = (const float*)d_in[4];
  float* out = (float*)d_out;

  char* ws = (char*)d_ws;
  f16*   Opart = (f16*)(ws);                               // 40 MiB
  float* Mpart = (float*)(ws + (40u << 20));               // 160 KiB
  float* Lpart = (float*)(ws + (41u << 20));               // 160 KiB
  int*   TileP = (int*)(ws + (42u << 20));                 // 1.25 KiB
  f16* Qh = (f16*)(ws + (43u << 20));                      // 8 MiB (pre-scaled)
  f16* KB = (f16*)(ws + (51u << 20));                      // 8 MiB QKT-frag-packed
  f16* VB = (f16*)(ws + (59u << 20));                      // 8 MiB PV-frag-packed
  f16* Xh = (f16*)(ws + (67u << 20));                      // 8 MiB
  f16* Wh = (f16*)(ws + (75u << 20));                      // 1.5 MiB

  k_convert<<<4864, 256, 0, stream>>>(X, Wq, Wk, Wv, Xh, Wh, TileP);
  dim3 gp(64, 12);
  k_proj<<<gp, 256, 0, stream>>>(Xh, Wh, Qh, KB, VB);
  k_flash<<<256, 512, 0, stream>>>(Qh, KB, VB, Opart, Mpart, Lpart, TileP);
  k_reduce<<<256, 256, 0, stream>>>(Opart, Mpart, Lpart, TileP, out);
}